// Round 3
// baseline (235.050 us; speedup 1.0000x reference)
//
#include <hip/hip_runtime.h>

// Problem constants (match reference)
#define S_LEN 4096
#define DMODEL 1024
#define NH 16
#define DH 64
#define WIN 256
#define NQKV 3072  // fused QKV output width

typedef __attribute__((ext_vector_type(8))) short short8;
typedef __attribute__((ext_vector_type(4))) short sh4;
typedef __attribute__((ext_vector_type(4))) float floatx4;

__device__ __forceinline__ ushort f2bf(float f) {
    union { float f; unsigned int i; } x;
    x.f = f;
    unsigned int r = x.i + 0x7FFFu + ((x.i >> 16) & 1u);  // RNE
    return (ushort)(r >> 16);
}

// ---------------------------------------------------------------------------
// Fused fp32 -> bf16 convert for x, wq, wk, wv, wo in ONE dispatch.
// ---------------------------------------------------------------------------
__global__ __launch_bounds__(256) void cvt_all(const float* __restrict__ x,
                                               const float* __restrict__ wq,
                                               const float* __restrict__ wk,
                                               const float* __restrict__ wv,
                                               const float* __restrict__ wo,
                                               ushort* __restrict__ xb,
                                               ushort* __restrict__ W3b,
                                               ushort* __restrict__ wob,
                                               int nx8, int nw8) {
    int i = blockIdx.x * 256 + threadIdx.x;
    const float* src;
    ushort* dst;
    if (i < nx8) {
        src = x + (size_t)i * 8;            dst = xb + (size_t)i * 8;
    } else {
        int j = i - nx8;
        int which = j / nw8, r = j - which * nw8;
        if (which >= 4) return;
        const float* w4[4] = {wq, wk, wv, wo};
        src = w4[which] + (size_t)r * 8;
        dst = (which == 3 ? wob : W3b + (size_t)which * nw8 * 8) + (size_t)r * 8;
    }
    floatx4 f0 = *(const floatx4*)src;
    floatx4 f1 = *(const floatx4*)(src + 4);
    short8 v;
#pragma unroll
    for (int e = 0; e < 4; ++e) v[e] = (short)f2bf(f0[e]);
#pragma unroll
    for (int e = 0; e < 4; ++e) v[4 + e] = (short)f2bf(f1[e]);
    *(short8*)dst = v;
}

// ---------------------------------------------------------------------------
// Sync / wait primitives for the pipelined GEMMs.
// ---------------------------------------------------------------------------
#define GLOAD16(src, dst)                                                     \
    __builtin_amdgcn_global_load_lds(                                         \
        (const __attribute__((address_space(1))) void*)(src),                 \
        (__attribute__((address_space(3))) void*)(dst), 16, 0, 0)
#define WAITV6 asm volatile("s_waitcnt vmcnt(6)" ::: "memory")
#define WAITV4 asm volatile("s_waitcnt vmcnt(4)" ::: "memory")
#define WAITV2 asm volatile("s_waitcnt vmcnt(2)" ::: "memory")
#define WAITV0 asm volatile("s_waitcnt vmcnt(0)" ::: "memory")
#define BARR   asm volatile("s_barrier" ::: "memory")
#define WAITL                                                                 \
    do {                                                                      \
        asm volatile("s_waitcnt lgkmcnt(0)" ::: "memory");                    \
        __builtin_amdgcn_sched_barrier(0);                                    \
    } while (0)

// ---------------------------------------------------------------------------
// 256x256 8-wave 4-phase GEMM with pre-read pipelining (R3).
//   Same verified geometry/staging/swizzle as R2 (0 bank conflicts).
//   Schedule change: each phase's fragment ds_reads are issued one phase
//   EARLY (after the previous phase's MFMA), so read issue+latency hides
//   under the end-barrier + next phase's stage/vmcnt/mid-barrier, and each
//   lgkmcnt(0) waits ~nothing.
//   Cross-wave visibility rule: a ds_read of unit X follows a barrier
//   before which EVERY wave executed a vmcnt proving its own X-loads
//   landed. Ledger (stage order A0,B0,B1,A1 at P1..P4 for tile t+1):
//     P1: vmcnt(4)  proves B1(t)   -> P1-post pre-read of b1
//     P2: vmcnt(4)  proves A1(t)   -> P2-post pre-read of aR(A1)
//     P3: no wait
//     P4: vmcnt(6)  proves A0(t+1) -> P4-post pre-read of aR(A0')
//         post-MFMA vmcnt(4) proves B0(t+1) before end barrier
//           -> next P1-top read of b0
//   Never drains to 0 mid-loop; epilogue uses exact vmcnt(2)/vmcnt(0).
// ---------------------------------------------------------------------------
template <bool OUTF32>
__global__ __launch_bounds__(512, 2) void gemm256(const ushort* __restrict__ A,
                                                  const ushort* __restrict__ W,
                                                  void* __restrict__ Cout,
                                                  int M, int N, int K) {
    __shared__ __align__(16) ushort AS[2][2][128 * 64];  // 64 KiB
    __shared__ __align__(16) ushort BS[2][2][128 * 64];  // 64 KiB

    const int tid = threadIdx.x;
    const int w = tid >> 6, l = tid & 63;
    const int lm = l & 15, quad = l >> 4, l7 = l & 7;
    const int mh = w >> 2;   // wave M-half (0/1)
    const int wq = w & 3;    // wave N-quarter (0..3)

    // XCD-aware block swizzle (bijective; gridDim.y % 8 == 0 here).
    int bx, by;
    {
        const int nbx = gridDim.x, nby = gridDim.y;
        if ((nby & 7) == 0) {
            const int lin = blockIdx.y * nbx + blockIdx.x;
            const int rpb = nby >> 3;
            const int xcd = lin & 7, idx = lin >> 3;
            bx = idx / rpb;
            by = xcd * rpb + (idx - bx * rpb);
        } else {
            bx = blockIdx.x;
            by = blockIdx.y;
        }
    }
    const int bm0 = by * 256, bn0 = bx * 256;

    const ushort* Ag = A + (size_t)bm0 * K;
    const ushort* Wg = W + (size_t)bn0 * K;

    // Per-thread staging addresses: chunk c = p*512+tid (16 B each),
    // riu = c>>3 (row-in-unit), k-seg = (c&7)^(riu&7)  [inverse of read swz].
    int ksOff[2], aRowB[2], bRowB[2];
#pragma unroll
    for (int p = 0; p < 2; ++p) {
        int c = p * 512 + tid, riu = c >> 3;
        ksOff[p] = ((c & 7) ^ (riu & 7)) * 8;
        aRowB[p] = (riu >> 6) * 128 + (riu & 63);  // + u*64 at issue
        bRowB[p] = (riu >> 5) * 64 + (riu & 31);   // + u*32 at issue
    }

    auto stA = [&](int bf, int u, int k0) {
#pragma unroll
        for (int p = 0; p < 2; ++p)
            GLOAD16(Ag + (size_t)(aRowB[p] + u * 64) * K + k0 + ksOff[p],
                    &AS[bf][u][(p * 512 + tid) * 8]);
    };
    auto stB = [&](int bf, int u, int k0) {
#pragma unroll
        for (int p = 0; p < 2; ++p)
            GLOAD16(Wg + (size_t)(bRowB[p] + u * 32) * K + k0 + ksOff[p],
                    &BS[bf][u][(p * 512 + tid) * 8]);
    };

    const int s0 = (quad ^ l7) * 8;        // slot for kk=0
    const int s1 = ((4 + quad) ^ l7) * 8;  // slot for kk=1

    floatx4 acc[8][4] = {};
    short8 aR[4][2], b0[2][2], b1[2][2];

    auto rdA = [&](int bf, int g, short8(&r)[4][2]) {
#pragma unroll
        for (int m = 0; m < 4; ++m) {
            const ushort* p = &AS[bf][g][(mh * 64 + m * 16 + lm) * 64];
            r[m][0] = *(const short8*)(p + s0);
            r[m][1] = *(const short8*)(p + s1);
        }
    };
    auto rdB = [&](int bf, int g, short8(&r)[2][2]) {
#pragma unroll
        for (int n = 0; n < 2; ++n) {
            const ushort* p = &BS[bf][g][(wq * 32 + n * 16 + lm) * 64];
            r[n][0] = *(const short8*)(p + s0);
            r[n][1] = *(const short8*)(p + s1);
        }
    };

#define MMAQ(AF, BF_, GM, GN)                                                  \
    do {                                                                       \
        __builtin_amdgcn_s_setprio(1);                                         \
        _Pragma("unroll") for (int m_ = 0; m_ < 4; ++m_)                       \
            _Pragma("unroll") for (int n_ = 0; n_ < 2; ++n_) {                 \
            acc[(GM)*4 + m_][(GN)*2 + n_] =                                    \
                __builtin_amdgcn_mfma_f32_16x16x32_bf16(                       \
                    AF[m_][0], BF_[n_][0], acc[(GM)*4 + m_][(GN)*2 + n_], 0,   \
                    0, 0);                                                     \
            acc[(GM)*4 + m_][(GN)*2 + n_] =                                    \
                __builtin_amdgcn_mfma_f32_16x16x32_bf16(                       \
                    AF[m_][1], BF_[n_][1], acc[(GM)*4 + m_][(GN)*2 + n_], 0,   \
                    0, 0);                                                     \
        }                                                                      \
        __builtin_amdgcn_s_setprio(0);                                         \
    } while (0)

    // Prologue: stage tile 0 in need-order; A0,B0 proven landed per-wave,
    // then barrier establishes cross-wave visibility; pre-read A0 frags.
    stA(0, 0, 0);
    stB(0, 0, 0);
    stB(0, 1, 0);
    stA(0, 1, 0);
    WAITV4;
    BARR;
    rdA(0, 0, aR);

    const int nt = K >> 6;  // 16
    for (int t = 0; t < nt; ++t) {
        const int bf = t & 1, nb = bf ^ 1, kn = (t + 1) << 6;
        const bool nl = (t + 1 < nt);
        // ---- P1: MFMA (M0xN0) on aR(A0),b0(B0); stage A0(t+1)
        rdB(bf, 0, b0);  // B0(t): proven by all waves' post-MFMA vmcnt(4)@P4(t-1)
        if (nl) { stA(nb, 0, kn); WAITV4; } else { WAITV2; }  // proves B1(t)
        BARR;
        WAITL;
        MMAQ(aR, b0, 0, 0);
        rdB(bf, 1, b1);  // pre-read for P2 (B1 proven pre-mid-barrier)
        BARR;
        // ---- P2: MFMA (M0xN1); stage B0(t+1)
        if (nl) { stB(nb, 0, kn); WAITV4; } else { WAITV0; }  // proves A1(t)
        BARR;
        WAITL;
        MMAQ(aR, b1, 0, 1);
        rdA(bf, 1, aR);  // pre-read for P3 (A1 proven pre-mid-barrier)
        BARR;
        // ---- P3: MFMA (M1xN1); stage B1(t+1); no vm wait
        if (nl) stB(nb, 1, kn);
        BARR;
        WAITL;
        MMAQ(aR, b1, 1, 1);
        BARR;
        // ---- P4: MFMA (M1xN0); stage A1(t+1)
        if (nl) { stA(nb, 1, kn); WAITV6; }  // proves A0(t+1)
        BARR;
        WAITL;
        MMAQ(aR, b0, 1, 0);
        if (nl) {
            rdA(nb, 0, aR);  // pre-read next P1's A frags (A0' proven)
            WAITV4;          // prove B0(t+1) per-wave before end barrier
        }
        BARR;
    }

#pragma unroll
    for (int mi = 0; mi < 8; ++mi)
#pragma unroll
        for (int ni = 0; ni < 4; ++ni)
#pragma unroll
            for (int r = 0; r < 4; ++r) {
                int row = bm0 + mh * 128 + mi * 16 + quad * 4 + r;
                int col = bn0 + wq * 64 + ni * 16 + lm;
                if constexpr (OUTF32)
                    ((float*)Cout)[(size_t)row * N + col] = acc[mi][ni][r];
                else
                    ((ushort*)Cout)[(size_t)row * N + col] = f2bf(acc[mi][ni][r]);
            }
#undef MMAQ
}

// ---------------------------------------------------------------------------
// R0-proven 128x256 BK=64 single-buffer GEMM (zero bank conflicts) + XCD
// swizzle — used for the output projection (grid 256 = 1 block/CU).
// ---------------------------------------------------------------------------
template <bool OUTF32>
__global__ __launch_bounds__(256, 2) void gemm128(const ushort* __restrict__ A,
                                                  const ushort* __restrict__ W,
                                                  void* __restrict__ Cout,
                                                  int M, int N, int K) {
    __shared__ __align__(16) ushort As[128 * 64];  // 16 KB
    __shared__ __align__(16) ushort Ws[256 * 64];  // 32 KB

    const int tid = threadIdx.x;
    const int w = tid >> 6, l = tid & 63;

    int bx, by;
    {
        const int nbx = gridDim.x, nby = gridDim.y;
        if ((nby & 7) == 0) {
            const int lin = blockIdx.y * nbx + blockIdx.x;
            const int rpb = nby >> 3;
            const int xcd = lin & 7, idx = lin >> 3;
            bx = idx / rpb;
            by = xcd * rpb + (idx - bx * rpb);
        } else {
            bx = blockIdx.x;
            by = blockIdx.y;
        }
    }
    const int bm0 = by * 128, bn0 = bx * 256;
    const int wm = (w >> 1) * 64, wn = (w & 1) * 128;
    const int lm = l & 15, quad = l >> 4;

    floatx4 acc[4][8] = {};

    // Staging: chunk c (16 B): row = c>>3, pos = c&7, global seg = pos^(row&7).
    int arow[4], acol[4];
#pragma unroll
    for (int p = 0; p < 4; ++p) {
        int c = p * 256 + tid;
        arow[p] = c >> 3;
        acol[p] = (((c & 7) ^ (arow[p] & 7))) * 8;
    }
    int wrow[8], wcol[8];
#pragma unroll
    for (int p = 0; p < 8; ++p) {
        int c = p * 256 + tid;
        wrow[p] = c >> 3;
        wcol[p] = (((c & 7) ^ (wrow[p] & 7))) * 8;
    }

    for (int k0 = 0; k0 < K; k0 += 64) {
#pragma unroll
        for (int p = 0; p < 4; ++p)
            GLOAD16(A + (size_t)(bm0 + arow[p]) * K + k0 + acol[p],
                    As + p * 2048 + tid * 8);
#pragma unroll
        for (int p = 0; p < 8; ++p)
            GLOAD16(W + (size_t)(bn0 + wrow[p]) * K + k0 + wcol[p],
                    Ws + p * 2048 + tid * 8);
        __syncthreads();  // drains vmcnt(0): staging complete

#pragma unroll
        for (int kk = 0; kk < 2; ++kk) {
            const int sseg = ((kk * 4 + quad) ^ (lm & 7)) * 8;
            short8 af[4], wf[8];
#pragma unroll
            for (int mi = 0; mi < 4; ++mi)
                af[mi] = *(const short8*)&As[(wm + mi * 16 + lm) * 64 + sseg];
#pragma unroll
            for (int ni = 0; ni < 8; ++ni)
                wf[ni] = *(const short8*)&Ws[(wn + ni * 16 + lm) * 64 + sseg];
#pragma unroll
            for (int mi = 0; mi < 4; ++mi)
#pragma unroll
                for (int ni = 0; ni < 8; ++ni)
                    acc[mi][ni] = __builtin_amdgcn_mfma_f32_16x16x32_bf16(
                        af[mi], wf[ni], acc[mi][ni], 0, 0, 0);
        }
        __syncthreads();  // frag reads done before next staging overwrites
    }

#pragma unroll
    for (int mi = 0; mi < 4; ++mi)
#pragma unroll
        for (int ni = 0; ni < 8; ++ni)
#pragma unroll
            for (int r = 0; r < 4; ++r) {
                int row = bm0 + wm + mi * 16 + quad * 4 + r;
                int col = bn0 + wn + ni * 16 + lm;
                if constexpr (OUTF32)
                    ((float*)Cout)[(size_t)row * N + col] = acc[mi][ni][r];
                else
                    ((ushort*)Cout)[(size_t)row * N + col] = f2bf(acc[mi][ni][r]);
            }
}

// ---------------------------------------------------------------------------
// MFMA sliding-window attention over fused QKV layout [M][3072]. (unchanged)
// ---------------------------------------------------------------------------
#define KSP 72    // Ks row stride (shorts)
#define VTP 136   // Vt row stride (shorts)
#define PSP 40    // Ps row stride (shorts)

__global__ __launch_bounds__(256) void swattn_mfma(const ushort* __restrict__ QKV,
                                                   ushort* __restrict__ O) {
    __shared__ __align__(16) ushort Ks[128 * KSP];        // 18432 B  [key][d]
    __shared__ __align__(16) ushort Vt[64 * VTP];         // 17408 B  [pi(d)][key]
    __shared__ __align__(16) ushort Ps[2][4 * 64 * PSP];  // 40960 B  dbuf per-wave [q][key32]
    __shared__ __align__(16) float lW[256];               // 1024 B

    const int j = blockIdx.x, h = blockIdx.y, b = blockIdx.z;
    const int tid = threadIdx.x;
    const int w = tid >> 6, l = tid & 63;
    const int quad = l >> 4, lc = l & 15;

    const size_t base = (size_t)b * S_LEN * NQKV + (size_t)h * DH;
    const ushort* Qp = QKV + base;               // row stride NQKV
    const ushort* Kp = QKV + base + DMODEL;
    const ushort* Vp = QKV + base + 2 * DMODEL;

    short8 qf[4][2];
#pragma unroll
    for (int nq = 0; nq < 4; ++nq)
#pragma unroll
        for (int kk = 0; kk < 2; ++kk)
            qf[nq][kk] = *(const short8*)(Qp +
                (size_t)(j * 256 + w * 64 + nq * 16 + lc) * NQKV + kk * 32 + quad * 8);

    floatx4 o[4][4] = {};
    float lsum[4] = {0.f, 0.f, 0.f, 0.f};

    const float sscale = 0.18033688011112042f;  // log2(e)/sqrt(64)
    const float M0 = 2.0f;                      // fixed shift (exact: shift-invariance)
    const int qlo = w * 64, qhi = w * 64 + 63;

    for (int c = 0; c < 4; ++c) {
        const int kg0 = (j - 1) * 256 + c * 128;
        if (kg0 < 0) continue;
        __syncthreads();
#pragma unroll
        for (int i = 0; i < 4; ++i) {
            int cc = i * 256 + tid, key = cc >> 3, seg = cc & 7;
            *(short8*)&Ks[key * KSP + seg * 8] =
                *(const short8*)(Kp + (size_t)(kg0 + key) * NQKV + seg * 8);
            short8 vv = *(const short8*)(Vp + (size_t)(kg0 + key) * NQKV + seg * 8);
#pragma unroll
            for (int e = 0; e < 8; ++e)
                Vt[(e * 8 + seg) * VTP + key] = (ushort)vv[e];  // pi(seg*8+e)=e*8+seg
        }
        __syncthreads();

        const int krel0 = c * 128 - 256;
#pragma unroll
        for (int g = 0; g < 4; ++g) {
            const int k0 = krel0 + g * 32;
            if (k0 > qhi || k0 + 31 < qlo - 255) continue;
            ushort* Pw = &Ps[g & 1][w * 64 * PSP];

            // S^T = K·Q^T : D[key][q], with fully-masked-subtile skip
            floatx4 st[2][4];
            const floatx4 zero = {};
#pragma unroll
            for (int kt = 0; kt < 2; ++kt) {
                short8 kf0 = *(const short8*)&Ks[(g * 32 + kt * 16 + lc) * KSP + quad * 8];
                short8 kf1 = *(const short8*)&Ks[(g * 32 + kt * 16 + lc) * KSP + 32 + quad * 8];
#pragma unroll
                for (int nq = 0; nq < 4; ++nq) {
                    int kmin = k0 + kt * 16, qmin = qlo + nq * 16;
                    if (kmin > qmin + 15 || kmin + 270 < qmin) {  // fully masked
                        st[kt][nq] = zero;
                        continue;
                    }
                    st[kt][nq] = __builtin_amdgcn_mfma_f32_16x16x32_bf16(kf0, qf[nq][0], zero, 0, 0, 0);
                    st[kt][nq] = __builtin_amdgcn_mfma_f32_16x16x32_bf16(kf1, qf[nq][1], st[kt][nq], 0, 0, 0);
                }
            }
#pragma unroll
            for (int kt = 0; kt < 2; ++kt)
#pragma unroll
                for (int nq = 0; nq < 4; ++nq) {
                    sh4 pv;
                    int kmin = k0 + kt * 16, qmin = qlo + nq * 16;
                    if (kmin > qmin + 15 || kmin + 270 < qmin) {           // fully masked
                        pv[0] = pv[1] = pv[2] = pv[3] = 0;
                    } else if (kmin + 15 <= qmin && kmin + 240 >= qmin) {  // interior: no mask
#pragma unroll
                        for (int r = 0; r < 4; ++r) {
                            float p = exp2f(st[kt][nq][r] * sscale - M0);
                            lsum[nq] += p;
                            pv[r] = (short)f2bf(p);
                        }
                    } else {                                               // boundary
#pragma unroll
                        for (int r = 0; r < 4; ++r) {
                            int krel = kmin + quad * 4 + r;  // C row = key
                            int qrel = qmin + lc;            // C col = q
                            bool valid = (krel <= qrel) && (krel + 255 >= qrel);
                            float p = valid ? exp2f(st[kt][nq][r] * sscale - M0) : 0.f;
                            lsum[nq] += p;
                            pv[r] = (short)f2bf(p);
                        }
                    }
                    *(sh4*)&Pw[(nq * 16 + lc) * PSP + kt * 16 + quad * 4] = pv;
                }
            __threadfence_block();  // P writes visible before lane-crossed reads

            // O += P·V : A=P[q][key] from Ps, B=V^T[d][key] from Vt (pi rows)
            short8 vf[4];
#pragma unroll
            for (int nd = 0; nd < 4; ++nd) {
                int prow = (lc & 7) * 8 + nd * 2 + (lc >> 3);  // pi(nd*16+lc)
                vf[nd] = *(const short8*)&Vt[prow * VTP + g * 32 + quad * 8];
            }
#pragma unroll
            for (int mq = 0; mq < 4; ++mq) {
                int qmin = qlo + mq * 16;
                if (k0 > qmin + 15 || k0 + 286 < qmin) continue;  // group fully masked
                short8 pf = *(const short8*)&Pw[(mq * 16 + lc) * PSP + quad * 8];
#pragma unroll
                for (int nd = 0; nd < 4; ++nd)
                    o[mq][nd] = __builtin_amdgcn_mfma_f32_16x16x32_bf16(pf, vf[nd], o[mq][nd], 0, 0, 0);
            }
            // no trailing fence: next group writes the OTHER Ps buffer; the
            // group-after-next is separated by the next group's fence.
        }
    }

#pragma unroll
    for (int nq = 0; nq < 4; ++nq) {
        lsum[nq] += __shfl_xor(lsum[nq], 16);
        lsum[nq] += __shfl_xor(lsum[nq], 32);
    }
    if (l < 16) {
#pragma unroll
        for (int nq = 0; nq < 4; ++nq) lW[w * 64 + nq * 16 + l] = lsum[nq];
    }
    __threadfence_block();
#pragma unroll
    for (int mq = 0; mq < 4; ++mq) {
        floatx4 lv = *(const floatx4*)&lW[w * 64 + mq * 16 + quad * 4];
#pragma unroll
        for (int r = 0; r < 4; ++r) {
            float inv = 1.f / lv[r];
            int token = j * 256 + w * 64 + mq * 16 + quad * 4 + r;
#pragma unroll
            for (int nd = 0; nd < 4; ++nd)
                O[(size_t)b * S_LEN * DMODEL + (size_t)token * DMODEL + h * DH + nd * 16 + lc] =
                    f2bf(o[mq][nd][r] * inv);
        }
    }
}

// ---------------------------------------------------------------------------
extern "C" void kernel_launch(void* const* d_in, const int* in_sizes, int n_in,
                              void* d_out, int out_size, void* d_ws, size_t ws_size,
                              hipStream_t stream) {
    const float* x  = (const float*)d_in[0];
    const float* wq = (const float*)d_in[1];
    const float* wk = (const float*)d_in[2];
    const float* wv = (const float*)d_in[3];
    const float* wo = (const float*)d_in[4];
    float* out = (float*)d_out;

    const int D = DMODEL;
    const int M = in_sizes[0] / D;  // B*S = 8192
    const int Bb = M / S_LEN;       // 2

    ushort* xb   = (ushort*)d_ws;
    ushort* W3b  = xb + (size_t)M * D;
    ushort* wob  = W3b + (size_t)NQKV * D;
    ushort* QKVb = wob + (size_t)D * D;
    ushort* Ob   = xb;  // overlay: xb dead after QKV GEMM

    const int nx8 = M * D / 8, nw8 = D * D / 8;
    const int ntot = nx8 + 4 * nw8;
    cvt_all<<<dim3((ntot + 255) / 256), dim3(256), 0, stream>>>(
        x, wq, wk, wv, wo, xb, W3b, wob, nx8, nw8);

    // Fused QKV projection: [M,3072] = xb @ W3b^T  (256² pre-read pipeline)
    gemm256<false><<<dim3(NQKV / 256, M / 256), dim3(512), 0, stream>>>(
        xb, W3b, QKVb, M, NQKV, D);

    swattn_mfma<<<dim3(S_LEN / WIN, NH, Bb), dim3(256), 0, stream>>>(QKVb, Ob);

    // Output projection: out[M,1024] = Ob @ wob^T (fp32 out, proven structure)
    gemm128<true><<<dim3(D / 256, M / 128), dim3(256), 0, stream>>>(
        Ob, wob, out, M, D, D);
}

// Round 4
// 229.738 us; speedup vs baseline: 1.0231x; 1.0231x over previous
//
#include <hip/hip_runtime.h>

// Problem constants (match reference)
#define S_LEN 4096
#define DMODEL 1024
#define NH 16
#define DH 64
#define WIN 256
#define NQKV 3072  // fused QKV output width

typedef __attribute__((ext_vector_type(8))) short short8;
typedef __attribute__((ext_vector_type(4))) short sh4;
typedef __attribute__((ext_vector_type(4))) float floatx4;

__device__ __forceinline__ ushort f2bf(float f) {
    union { float f; unsigned int i; } x;
    x.f = f;
    unsigned int r = x.i + 0x7FFFu + ((x.i >> 16) & 1u);  // RNE
    return (ushort)(r >> 16);
}

// ---------------------------------------------------------------------------
// Fused fp32 -> bf16 convert for x, wq, wk, wv, wo in ONE dispatch.
// ---------------------------------------------------------------------------
__global__ __launch_bounds__(256) void cvt_all(const float* __restrict__ x,
                                               const float* __restrict__ wq,
                                               const float* __restrict__ wk,
                                               const float* __restrict__ wv,
                                               const float* __restrict__ wo,
                                               ushort* __restrict__ xb,
                                               ushort* __restrict__ W3b,
                                               ushort* __restrict__ wob,
                                               int nx8, int nw8) {
    int i = blockIdx.x * 256 + threadIdx.x;
    const float* src;
    ushort* dst;
    if (i < nx8) {
        src = x + (size_t)i * 8;            dst = xb + (size_t)i * 8;
    } else {
        int j = i - nx8;
        int which = j / nw8, r = j - which * nw8;
        if (which >= 4) return;
        const float* w4[4] = {wq, wk, wv, wo};
        src = w4[which] + (size_t)r * 8;
        dst = (which == 3 ? wob : W3b + (size_t)which * nw8 * 8) + (size_t)r * 8;
    }
    floatx4 f0 = *(const floatx4*)src;
    floatx4 f1 = *(const floatx4*)(src + 4);
    short8 v;
#pragma unroll
    for (int e = 0; e < 4; ++e) v[e] = (short)f2bf(f0[e]);
#pragma unroll
    for (int e = 0; e < 4; ++e) v[4 + e] = (short)f2bf(f1[e]);
    *(short8*)dst = v;
}

// ---------------------------------------------------------------------------
#define GLOAD16(src, dst)                                                     \
    __builtin_amdgcn_global_load_lds(                                         \
        (const __attribute__((address_space(1))) void*)(src),                 \
        (__attribute__((address_space(3))) void*)(dst), 16, 0, 0)

// ---------------------------------------------------------------------------
// R0-proven 128x256 BK=64 single-buffer GEMM (measured 63.5us/811TF on the
// QKV shape, zero bank conflicts) + XCD-aware swizzle (proven FETCH 78->41MB
// on this shape in R1). Used for BOTH the QKV projection and the output
// projection. 2-barrier loop: best measured structure for this problem
// (256^2 4-phase ports measured SLOWER: 70.8/71.6us, R2/R3).
// ---------------------------------------------------------------------------
template <bool OUTF32>
__global__ __launch_bounds__(256, 2) void gemm128(const ushort* __restrict__ A,
                                                  const ushort* __restrict__ W,
                                                  void* __restrict__ Cout,
                                                  int M, int N, int K) {
    __shared__ __align__(16) ushort As[128 * 64];  // 16 KB
    __shared__ __align__(16) ushort Ws[256 * 64];  // 32 KB

    const int tid = threadIdx.x;
    const int w = tid >> 6, l = tid & 63;

    // XCD-aware block swizzle (bijective when gridDim.y % 8 == 0).
    int bx, by;
    {
        const int nbx = gridDim.x, nby = gridDim.y;
        if ((nby & 7) == 0) {
            const int lin = blockIdx.y * nbx + blockIdx.x;
            const int rpb = nby >> 3;
            const int xcd = lin & 7, idx = lin >> 3;
            bx = idx / rpb;
            by = xcd * rpb + (idx - bx * rpb);
        } else {
            bx = blockIdx.x;
            by = blockIdx.y;
        }
    }
    const int bm0 = by * 128, bn0 = bx * 256;
    const int wm = (w >> 1) * 64, wn = (w & 1) * 128;
    const int lm = l & 15, quad = l >> 4;

    floatx4 acc[4][8] = {};

    // Staging: chunk c (16 B): row = c>>3, pos = c&7, global seg = pos^(row&7)
    // (both-sides XOR swizzle; reads below use the same involution -> 0 LDS
    //  bank conflicts, measured).
    int arow[4], acol[4];
#pragma unroll
    for (int p = 0; p < 4; ++p) {
        int c = p * 256 + tid;
        arow[p] = c >> 3;
        acol[p] = (((c & 7) ^ (arow[p] & 7))) * 8;
    }
    int wrow[8], wcol[8];
#pragma unroll
    for (int p = 0; p < 8; ++p) {
        int c = p * 256 + tid;
        wrow[p] = c >> 3;
        wcol[p] = (((c & 7) ^ (wrow[p] & 7))) * 8;
    }

    for (int k0 = 0; k0 < K; k0 += 64) {
#pragma unroll
        for (int p = 0; p < 4; ++p)
            GLOAD16(A + (size_t)(bm0 + arow[p]) * K + k0 + acol[p],
                    As + p * 2048 + tid * 8);
#pragma unroll
        for (int p = 0; p < 8; ++p)
            GLOAD16(W + (size_t)(bn0 + wrow[p]) * K + k0 + wcol[p],
                    Ws + p * 2048 + tid * 8);
        __syncthreads();  // drains vmcnt(0): staging complete

#pragma unroll
        for (int kk = 0; kk < 2; ++kk) {
            const int sseg = ((kk * 4 + quad) ^ (lm & 7)) * 8;
            short8 af[4], wf[8];
#pragma unroll
            for (int mi = 0; mi < 4; ++mi)
                af[mi] = *(const short8*)&As[(wm + mi * 16 + lm) * 64 + sseg];
#pragma unroll
            for (int ni = 0; ni < 8; ++ni)
                wf[ni] = *(const short8*)&Ws[(wn + ni * 16 + lm) * 64 + sseg];
#pragma unroll
            for (int mi = 0; mi < 4; ++mi)
#pragma unroll
                for (int ni = 0; ni < 8; ++ni)
                    acc[mi][ni] = __builtin_amdgcn_mfma_f32_16x16x32_bf16(
                        af[mi], wf[ni], acc[mi][ni], 0, 0, 0);
        }
        __syncthreads();  // frag reads done before next staging overwrites
    }

#pragma unroll
    for (int mi = 0; mi < 4; ++mi)
#pragma unroll
        for (int ni = 0; ni < 8; ++ni)
#pragma unroll
            for (int r = 0; r < 4; ++r) {
                int row = bm0 + wm + mi * 16 + quad * 4 + r;
                int col = bn0 + wn + ni * 16 + lm;
                if constexpr (OUTF32)
                    ((float*)Cout)[(size_t)row * N + col] = acc[mi][ni][r];
                else
                    ((ushort*)Cout)[(size_t)row * N + col] = f2bf(acc[mi][ni][r]);
            }
}

// ---------------------------------------------------------------------------
// MFMA sliding-window attention over fused QKV layout [M][3072].
// R4: K is no longer LDS-staged — K fragments are read directly from global
// (identical 16B/lane pattern to the proven direct Q loads; 4 lanes cover a
// full 64B line; K slice is L2-resident across the 4x wave reuse + j/j+1
// block reuse). This halves the per-c staging critical section; only the
// V-transpose (which genuinely needs the layout change) still stages.
// ---------------------------------------------------------------------------
#define VTP 136   // Vt row stride (shorts)
#define PSP 40    // Ps row stride (shorts)

__global__ __launch_bounds__(256) void swattn_mfma(const ushort* __restrict__ QKV,
                                                   ushort* __restrict__ O) {
    __shared__ __align__(16) ushort Vt[64 * VTP];         // 17408 B  [pi(d)][key]
    __shared__ __align__(16) ushort Ps[2][4 * 64 * PSP];  // 40960 B  dbuf per-wave [q][key32]
    __shared__ __align__(16) float lW[256];               // 1024 B

    const int j = blockIdx.x, h = blockIdx.y, b = blockIdx.z;
    const int tid = threadIdx.x;
    const int w = tid >> 6, l = tid & 63;
    const int quad = l >> 4, lc = l & 15;

    const size_t base = (size_t)b * S_LEN * NQKV + (size_t)h * DH;
    const ushort* Qp = QKV + base;               // row stride NQKV
    const ushort* Kp = QKV + base + DMODEL;
    const ushort* Vp = QKV + base + 2 * DMODEL;

    short8 qf[4][2];
#pragma unroll
    for (int nq = 0; nq < 4; ++nq)
#pragma unroll
        for (int kk = 0; kk < 2; ++kk)
            qf[nq][kk] = *(const short8*)(Qp +
                (size_t)(j * 256 + w * 64 + nq * 16 + lc) * NQKV + kk * 32 + quad * 8);

    floatx4 o[4][4] = {};
    float lsum[4] = {0.f, 0.f, 0.f, 0.f};

    const float sscale = 0.18033688011112042f;  // log2(e)/sqrt(64)
    const float M0 = 2.0f;                      // fixed shift (exact: shift-invariance)
    const int qlo = w * 64, qhi = w * 64 + 63;

    for (int c = 0; c < 4; ++c) {
        const int kg0 = (j - 1) * 256 + c * 128;
        if (kg0 < 0) continue;
        __syncthreads();  // prev c's Vt reads done before overwrite
#pragma unroll
        for (int i = 0; i < 4; ++i) {
            int cc = i * 256 + tid, key = cc >> 3, seg = cc & 7;
            short8 vv = *(const short8*)(Vp + (size_t)(kg0 + key) * NQKV + seg * 8);
#pragma unroll
            for (int e = 0; e < 8; ++e)
                Vt[(e * 8 + seg) * VTP + key] = (ushort)vv[e];  // pi(seg*8+e)=e*8+seg
        }
        __syncthreads();

        const int krel0 = c * 128 - 256;
#pragma unroll
        for (int g = 0; g < 4; ++g) {
            const int k0 = krel0 + g * 32;
            if (k0 > qhi || k0 + 31 < qlo - 255) continue;
            ushort* Pw = &Ps[g & 1][w * 64 * PSP];

            // S^T = K·Q^T : D[key][q], K fragments direct from global
            floatx4 st[2][4];
            const floatx4 zero = {};
#pragma unroll
            for (int kt = 0; kt < 2; ++kt) {
                const ushort* Kr = Kp + (size_t)(kg0 + g * 32 + kt * 16 + lc) * NQKV;
                short8 kf0 = *(const short8*)(Kr + quad * 8);
                short8 kf1 = *(const short8*)(Kr + 32 + quad * 8);
#pragma unroll
                for (int nq = 0; nq < 4; ++nq) {
                    int kmin = k0 + kt * 16, qmin = qlo + nq * 16;
                    if (kmin > qmin + 15 || kmin + 270 < qmin) {  // fully masked
                        st[kt][nq] = zero;
                        continue;
                    }
                    st[kt][nq] = __builtin_amdgcn_mfma_f32_16x16x32_bf16(kf0, qf[nq][0], zero, 0, 0, 0);
                    st[kt][nq] = __builtin_amdgcn_mfma_f32_16x16x32_bf16(kf1, qf[nq][1], st[kt][nq], 0, 0, 0);
                }
            }
#pragma unroll
            for (int kt = 0; kt < 2; ++kt)
#pragma unroll
                for (int nq = 0; nq < 4; ++nq) {
                    sh4 pv;
                    int kmin = k0 + kt * 16, qmin = qlo + nq * 16;
                    if (kmin > qmin + 15 || kmin + 270 < qmin) {           // fully masked
                        pv[0] = pv[1] = pv[2] = pv[3] = 0;
                    } else if (kmin + 15 <= qmin && kmin + 240 >= qmin) {  // interior: no mask
#pragma unroll
                        for (int r = 0; r < 4; ++r) {
                            float p = exp2f(st[kt][nq][r] * sscale - M0);
                            lsum[nq] += p;
                            pv[r] = (short)f2bf(p);
                        }
                    } else {                                               // boundary
#pragma unroll
                        for (int r = 0; r < 4; ++r) {
                            int krel = kmin + quad * 4 + r;  // C row = key
                            int qrel = qmin + lc;            // C col = q
                            bool valid = (krel <= qrel) && (krel + 255 >= qrel);
                            float p = valid ? exp2f(st[kt][nq][r] * sscale - M0) : 0.f;
                            lsum[nq] += p;
                            pv[r] = (short)f2bf(p);
                        }
                    }
                    *(sh4*)&Pw[(nq * 16 + lc) * PSP + kt * 16 + quad * 4] = pv;
                }
            __threadfence_block();  // P writes visible before lane-crossed reads

            // O += P·V : A=P[q][key] from Ps, B=V^T[d][key] from Vt (pi rows)
            short8 vf[4];
#pragma unroll
            for (int nd = 0; nd < 4; ++nd) {
                int prow = (lc & 7) * 8 + nd * 2 + (lc >> 3);  // pi(nd*16+lc)
                vf[nd] = *(const short8*)&Vt[prow * VTP + g * 32 + quad * 8];
            }
#pragma unroll
            for (int mq = 0; mq < 4; ++mq) {
                int qmin = qlo + mq * 16;
                if (k0 > qmin + 15 || k0 + 286 < qmin) continue;  // group fully masked
                short8 pf = *(const short8*)&Pw[(mq * 16 + lc) * PSP + quad * 8];
#pragma unroll
                for (int nd = 0; nd < 4; ++nd)
                    o[mq][nd] = __builtin_amdgcn_mfma_f32_16x16x32_bf16(pf, vf[nd], o[mq][nd], 0, 0, 0);
            }
            // no trailing fence: next group writes the OTHER Ps buffer; the
            // group-after-next is separated by the next group's fence.
        }
    }

#pragma unroll
    for (int nq = 0; nq < 4; ++nq) {
        lsum[nq] += __shfl_xor(lsum[nq], 16);
        lsum[nq] += __shfl_xor(lsum[nq], 32);
    }
    if (l < 16) {
#pragma unroll
        for (int nq = 0; nq < 4; ++nq) lW[w * 64 + nq * 16 + l] = lsum[nq];
    }
    __threadfence_block();
#pragma unroll
    for (int mq = 0; mq < 4; ++mq) {
        floatx4 lv = *(const floatx4*)&lW[w * 64 + mq * 16 + quad * 4];
#pragma unroll
        for (int r = 0; r < 4; ++r) {
            float inv = 1.f / lv[r];
            int token = j * 256 + w * 64 + mq * 16 + quad * 4 + r;
#pragma unroll
            for (int nd = 0; nd < 4; ++nd)
                O[(size_t)b * S_LEN * DMODEL + (size_t)token * DMODEL + h * DH + nd * 16 + lc] =
                    f2bf(o[mq][nd][r] * inv);
        }
    }
}

// ---------------------------------------------------------------------------
extern "C" void kernel_launch(void* const* d_in, const int* in_sizes, int n_in,
                              void* d_out, int out_size, void* d_ws, size_t ws_size,
                              hipStream_t stream) {
    const float* x  = (const float*)d_in[0];
    const float* wq = (const float*)d_in[1];
    const float* wk = (const float*)d_in[2];
    const float* wv = (const float*)d_in[3];
    const float* wo = (const float*)d_in[4];
    float* out = (float*)d_out;

    const int D = DMODEL;
    const int M = in_sizes[0] / D;  // B*S = 8192
    const int Bb = M / S_LEN;       // 2

    ushort* xb   = (ushort*)d_ws;
    ushort* W3b  = xb + (size_t)M * D;
    ushort* wob  = W3b + (size_t)NQKV * D;
    ushort* QKVb = wob + (size_t)D * D;
    ushort* Ob   = xb;  // overlay: xb dead after QKV GEMM

    const int nx8 = M * D / 8, nw8 = D * D / 8;
    const int ntot = nx8 + 4 * nw8;
    cvt_all<<<dim3((ntot + 255) / 256), dim3(256), 0, stream>>>(
        x, wq, wk, wv, wo, xb, W3b, wob, nx8, nw8);

    // Fused QKV projection: [M,3072] = xb @ W3b^T (proven 128x256 BK=64)
    gemm128<false><<<dim3(NQKV / 256, M / 128), dim3(256), 0, stream>>>(
        xb, W3b, QKVb, M, NQKV, D);

    swattn_mfma<<<dim3(S_LEN / WIN, NH, Bb), dim3(256), 0, stream>>>(QKVb, Ob);

    // Output projection: out[M,1024] = Ob @ wob^T (fp32 out, same structure)
    gemm128<true><<<dim3(D / 256, M / 128), dim3(256), 0, stream>>>(
        Ob, wob, out, M, D, D);
}

// Round 5
// 226.099 us; speedup vs baseline: 1.0396x; 1.0161x over previous
//
#include <hip/hip_runtime.h>

// Problem constants (match reference)
#define S_LEN 4096
#define DMODEL 1024
#define NH 16
#define DH 64
#define WIN 256
#define NQKV 3072  // fused QKV output width

typedef __attribute__((ext_vector_type(8))) short short8;
typedef __attribute__((ext_vector_type(4))) short sh4;
typedef __attribute__((ext_vector_type(4))) float floatx4;

__device__ __forceinline__ ushort f2bf(float f) {
    union { float f; unsigned int i; } x;
    x.f = f;
    unsigned int r = x.i + 0x7FFFu + ((x.i >> 16) & 1u);  // RNE
    return (ushort)(r >> 16);
}

// ---------------------------------------------------------------------------
// Fused fp32 -> bf16 convert for x, wq, wk, wv, wo in ONE dispatch.
// ---------------------------------------------------------------------------
__global__ __launch_bounds__(256) void cvt_all(const float* __restrict__ x,
                                               const float* __restrict__ wq,
                                               const float* __restrict__ wk,
                                               const float* __restrict__ wv,
                                               const float* __restrict__ wo,
                                               ushort* __restrict__ xb,
                                               ushort* __restrict__ W3b,
                                               ushort* __restrict__ wob,
                                               int nx8, int nw8) {
    int i = blockIdx.x * 256 + threadIdx.x;
    const float* src;
    ushort* dst;
    if (i < nx8) {
        src = x + (size_t)i * 8;            dst = xb + (size_t)i * 8;
    } else {
        int j = i - nx8;
        int which = j / nw8, r = j - which * nw8;
        if (which >= 4) return;
        const float* w4[4] = {wq, wk, wv, wo};
        src = w4[which] + (size_t)r * 8;
        dst = (which == 3 ? wob : W3b + (size_t)which * nw8 * 8) + (size_t)r * 8;
    }
    floatx4 f0 = *(const floatx4*)src;
    floatx4 f1 = *(const floatx4*)(src + 4);
    short8 v;
#pragma unroll
    for (int e = 0; e < 4; ++e) v[e] = (short)f2bf(f0[e]);
#pragma unroll
    for (int e = 0; e < 4; ++e) v[4 + e] = (short)f2bf(f1[e]);
    *(short8*)dst = v;
}

// ---------------------------------------------------------------------------
#define GLOAD16(src, dst)                                                     \
    __builtin_amdgcn_global_load_lds(                                         \
        (const __attribute__((address_space(1))) void*)(src),                 \
        (__attribute__((address_space(3))) void*)(dst), 16, 0, 0)

// ---------------------------------------------------------------------------
// Proven 128x256 BK=64 single-buffer GEMM (best measured QKV config:
// 61.5us / 849 TF effective, zero bank conflicts, FETCH 41MB with XCD
// swizzle). Used for BOTH projections. 2-barrier loop: deep-pipeline ports
// measured SLOWER on this shape (70.8/71.6us, R2/R3) — keep this.
// ---------------------------------------------------------------------------
template <bool OUTF32>
__global__ __launch_bounds__(256, 2) void gemm128(const ushort* __restrict__ A,
                                                  const ushort* __restrict__ W,
                                                  void* __restrict__ Cout,
                                                  int M, int N, int K) {
    __shared__ __align__(16) ushort As[128 * 64];  // 16 KB
    __shared__ __align__(16) ushort Ws[256 * 64];  // 32 KB

    const int tid = threadIdx.x;
    const int w = tid >> 6, l = tid & 63;

    // XCD-aware block swizzle (bijective when gridDim.y % 8 == 0).
    int bx, by;
    {
        const int nbx = gridDim.x, nby = gridDim.y;
        if ((nby & 7) == 0) {
            const int lin = blockIdx.y * nbx + blockIdx.x;
            const int rpb = nby >> 3;
            const int xcd = lin & 7, idx = lin >> 3;
            bx = idx / rpb;
            by = xcd * rpb + (idx - bx * rpb);
        } else {
            bx = blockIdx.x;
            by = blockIdx.y;
        }
    }
    const int bm0 = by * 128, bn0 = bx * 256;
    const int wm = (w >> 1) * 64, wn = (w & 1) * 128;
    const int lm = l & 15, quad = l >> 4;

    floatx4 acc[4][8] = {};

    // Staging: chunk c (16 B): row = c>>3, pos = c&7, global seg = pos^(row&7)
    // (both-sides XOR swizzle; reads use the same involution -> 0 conflicts).
    int arow[4], acol[4];
#pragma unroll
    for (int p = 0; p < 4; ++p) {
        int c = p * 256 + tid;
        arow[p] = c >> 3;
        acol[p] = (((c & 7) ^ (arow[p] & 7))) * 8;
    }
    int wrow[8], wcol[8];
#pragma unroll
    for (int p = 0; p < 8; ++p) {
        int c = p * 256 + tid;
        wrow[p] = c >> 3;
        wcol[p] = (((c & 7) ^ (wrow[p] & 7))) * 8;
    }

    for (int k0 = 0; k0 < K; k0 += 64) {
#pragma unroll
        for (int p = 0; p < 4; ++p)
            GLOAD16(A + (size_t)(bm0 + arow[p]) * K + k0 + acol[p],
                    As + p * 2048 + tid * 8);
#pragma unroll
        for (int p = 0; p < 8; ++p)
            GLOAD16(W + (size_t)(bn0 + wrow[p]) * K + k0 + wcol[p],
                    Ws + p * 2048 + tid * 8);
        __syncthreads();  // drains vmcnt(0): staging complete

#pragma unroll
        for (int kk = 0; kk < 2; ++kk) {
            const int sseg = ((kk * 4 + quad) ^ (lm & 7)) * 8;
            short8 af[4], wf[8];
#pragma unroll
            for (int mi = 0; mi < 4; ++mi)
                af[mi] = *(const short8*)&As[(wm + mi * 16 + lm) * 64 + sseg];
#pragma unroll
            for (int ni = 0; ni < 8; ++ni)
                wf[ni] = *(const short8*)&Ws[(wn + ni * 16 + lm) * 64 + sseg];
#pragma unroll
            for (int mi = 0; mi < 4; ++mi)
#pragma unroll
                for (int ni = 0; ni < 8; ++ni)
                    acc[mi][ni] = __builtin_amdgcn_mfma_f32_16x16x32_bf16(
                        af[mi], wf[ni], acc[mi][ni], 0, 0, 0);
        }
        __syncthreads();  // frag reads done before next staging overwrites
    }

#pragma unroll
    for (int mi = 0; mi < 4; ++mi)
#pragma unroll
        for (int ni = 0; ni < 8; ++ni)
#pragma unroll
            for (int r = 0; r < 4; ++r) {
                int row = bm0 + wm + mi * 16 + quad * 4 + r;
                int col = bn0 + wn + ni * 16 + lm;
                if constexpr (OUTF32)
                    ((float*)Cout)[(size_t)row * N + col] = acc[mi][ni][r];
                else
                    ((ushort*)Cout)[(size_t)row * N + col] = f2bf(acc[mi][ni][r]);
            }
}

// ---------------------------------------------------------------------------
// MFMA sliding-window attention over fused QKV layout [M][3072].
// R5: K staging REVERTED to LDS (R4's K-direct regressed 'elsewhere' ~5-7us:
// 4x redundant per-wave global issue). NEW: T14 async-stage split — chunk
// c+1's K/V global loads are issued into REGISTERS right after the staging
// barrier of chunk c, so they fly under compute(c); only the LDS writes
// remain between the barriers. No sync-structure change (loads don't touch
// LDS; kreg/vreg WAR is per-thread program order).
// ---------------------------------------------------------------------------
#define KSP 72    // Ks row stride (shorts)
#define VTP 136   // Vt row stride (shorts)
#define PSP 40    // Ps row stride (shorts)

__global__ __launch_bounds__(256) void swattn_mfma(const ushort* __restrict__ QKV,
                                                   ushort* __restrict__ O) {
    __shared__ __align__(16) ushort Ks[128 * KSP];        // 18432 B  [key][d]
    __shared__ __align__(16) ushort Vt[64 * VTP];         // 17408 B  [pi(d)][key]
    __shared__ __align__(16) ushort Ps[2][4 * 64 * PSP];  // 40960 B  dbuf per-wave [q][key32]
    __shared__ __align__(16) float lW[256];               // 1024 B

    const int j = blockIdx.x, h = blockIdx.y, b = blockIdx.z;
    const int tid = threadIdx.x;
    const int w = tid >> 6, l = tid & 63;
    const int quad = l >> 4, lc = l & 15;

    const size_t base = (size_t)b * S_LEN * NQKV + (size_t)h * DH;
    const ushort* Qp = QKV + base;               // row stride NQKV
    const ushort* Kp = QKV + base + DMODEL;
    const ushort* Vp = QKV + base + 2 * DMODEL;

    short8 qf[4][2];
#pragma unroll
    for (int nq = 0; nq < 4; ++nq)
#pragma unroll
        for (int kk = 0; kk < 2; ++kk)
            qf[nq][kk] = *(const short8*)(Qp +
                (size_t)(j * 256 + w * 64 + nq * 16 + lc) * NQKV + kk * 32 + quad * 8);

    floatx4 o[4][4] = {};
    float lsum[4] = {0.f, 0.f, 0.f, 0.f};

    const float sscale = 0.18033688011112042f;  // log2(e)/sqrt(64)
    const float M0 = 2.0f;                      // fixed shift (exact: shift-invariance)
    const int qlo = w * 64, qhi = w * 64 + 63;

    // Per-thread staging coordinates (chunk i: key = (i*256+tid)>>3, seg low3)
    int skey[4], sseg[4];
#pragma unroll
    for (int i = 0; i < 4; ++i) {
        int cc = i * 256 + tid;
        skey[i] = cc >> 3;
        sseg[i] = cc & 7;
    }

    short8 kreg[4], vreg[4];
    const int c0 = (j == 0) ? 2 : 0;  // first chunk with kg0 >= 0
    {
        const int kg0 = (j - 1) * 256 + c0 * 128;
#pragma unroll
        for (int i = 0; i < 4; ++i) {
            kreg[i] = *(const short8*)(Kp + (size_t)(kg0 + skey[i]) * NQKV + sseg[i] * 8);
            vreg[i] = *(const short8*)(Vp + (size_t)(kg0 + skey[i]) * NQKV + sseg[i] * 8);
        }
    }

    for (int c = c0; c < 4; ++c) {
        __syncthreads();  // prev chunk's Ks/Vt reads done before overwrite
#pragma unroll
        for (int i = 0; i < 4; ++i) {
            *(short8*)&Ks[skey[i] * KSP + sseg[i] * 8] = kreg[i];
#pragma unroll
            for (int e = 0; e < 8; ++e)
                Vt[(e * 8 + sseg[i]) * VTP + skey[i]] = (ushort)vreg[i][e];  // pi
        }
        __syncthreads();

        if (c < 3) {  // T14: issue next chunk's loads; they land under compute
            const int kg0n = (j - 1) * 256 + (c + 1) * 128;
#pragma unroll
            for (int i = 0; i < 4; ++i) {
                kreg[i] = *(const short8*)(Kp + (size_t)(kg0n + skey[i]) * NQKV + sseg[i] * 8);
                vreg[i] = *(const short8*)(Vp + (size_t)(kg0n + skey[i]) * NQKV + sseg[i] * 8);
            }
        }

        const int krel0 = c * 128 - 256;
#pragma unroll
        for (int g = 0; g < 4; ++g) {
            const int k0 = krel0 + g * 32;
            if (k0 > qhi || k0 + 31 < qlo - 255) continue;
            ushort* Pw = &Ps[g & 1][w * 64 * PSP];

            // S^T = K·Q^T : D[key][q], with fully-masked-subtile skip
            floatx4 st[2][4];
            const floatx4 zero = {};
#pragma unroll
            for (int kt = 0; kt < 2; ++kt) {
                short8 kf0 = *(const short8*)&Ks[(g * 32 + kt * 16 + lc) * KSP + quad * 8];
                short8 kf1 = *(const short8*)&Ks[(g * 32 + kt * 16 + lc) * KSP + 32 + quad * 8];
#pragma unroll
                for (int nq = 0; nq < 4; ++nq) {
                    int kmin = k0 + kt * 16, qmin = qlo + nq * 16;
                    if (kmin > qmin + 15 || kmin + 270 < qmin) {  // fully masked
                        st[kt][nq] = zero;
                        continue;
                    }
                    st[kt][nq] = __builtin_amdgcn_mfma_f32_16x16x32_bf16(kf0, qf[nq][0], zero, 0, 0, 0);
                    st[kt][nq] = __builtin_amdgcn_mfma_f32_16x16x32_bf16(kf1, qf[nq][1], st[kt][nq], 0, 0, 0);
                }
            }
#pragma unroll
            for (int kt = 0; kt < 2; ++kt)
#pragma unroll
                for (int nq = 0; nq < 4; ++nq) {
                    sh4 pv;
                    int kmin = k0 + kt * 16, qmin = qlo + nq * 16;
                    if (kmin > qmin + 15 || kmin + 270 < qmin) {           // fully masked
                        pv[0] = pv[1] = pv[2] = pv[3] = 0;
                    } else if (kmin + 15 <= qmin && kmin + 240 >= qmin) {  // interior: no mask
#pragma unroll
                        for (int r = 0; r < 4; ++r) {
                            float p = exp2f(st[kt][nq][r] * sscale - M0);
                            lsum[nq] += p;
                            pv[r] = (short)f2bf(p);
                        }
                    } else {                                               // boundary
#pragma unroll
                        for (int r = 0; r < 4; ++r) {
                            int krel = kmin + quad * 4 + r;  // C row = key
                            int qrel = qmin + lc;            // C col = q
                            bool valid = (krel <= qrel) && (krel + 255 >= qrel);
                            float p = valid ? exp2f(st[kt][nq][r] * sscale - M0) : 0.f;
                            lsum[nq] += p;
                            pv[r] = (short)f2bf(p);
                        }
                    }
                    *(sh4*)&Pw[(nq * 16 + lc) * PSP + kt * 16 + quad * 4] = pv;
                }
            __threadfence_block();  // P writes visible before lane-crossed reads

            // O += P·V : A=P[q][key] from Ps, B=V^T[d][key] from Vt (pi rows)
            short8 vf[4];
#pragma unroll
            for (int nd = 0; nd < 4; ++nd) {
                int prow = (lc & 7) * 8 + nd * 2 + (lc >> 3);  // pi(nd*16+lc)
                vf[nd] = *(const short8*)&Vt[prow * VTP + g * 32 + quad * 8];
            }
#pragma unroll
            for (int mq = 0; mq < 4; ++mq) {
                int qmin = qlo + mq * 16;
                if (k0 > qmin + 15 || k0 + 286 < qmin) continue;  // group fully masked
                short8 pf = *(const short8*)&Pw[(mq * 16 + lc) * PSP + quad * 8];
#pragma unroll
                for (int nd = 0; nd < 4; ++nd)
                    o[mq][nd] = __builtin_amdgcn_mfma_f32_16x16x32_bf16(pf, vf[nd], o[mq][nd], 0, 0, 0);
            }
            // no trailing fence: next group writes the OTHER Ps buffer; the
            // group-after-next is separated by the next group's fence.
        }
    }

#pragma unroll
    for (int nq = 0; nq < 4; ++nq) {
        lsum[nq] += __shfl_xor(lsum[nq], 16);
        lsum[nq] += __shfl_xor(lsum[nq], 32);
    }
    if (l < 16) {
#pragma unroll
        for (int nq = 0; nq < 4; ++nq) lW[w * 64 + nq * 16 + l] = lsum[nq];
    }
    __threadfence_block();
#pragma unroll
    for (int mq = 0; mq < 4; ++mq) {
        floatx4 lv = *(const floatx4*)&lW[w * 64 + mq * 16 + quad * 4];
#pragma unroll
        for (int r = 0; r < 4; ++r) {
            float inv = 1.f / lv[r];
            int token = j * 256 + w * 64 + mq * 16 + quad * 4 + r;
#pragma unroll
            for (int nd = 0; nd < 4; ++nd)
                O[(size_t)b * S_LEN * DMODEL + (size_t)token * DMODEL + h * DH + nd * 16 + lc] =
                    f2bf(o[mq][nd][r] * inv);
        }
    }
}

// ---------------------------------------------------------------------------
extern "C" void kernel_launch(void* const* d_in, const int* in_sizes, int n_in,
                              void* d_out, int out_size, void* d_ws, size_t ws_size,
                              hipStream_t stream) {
    const float* x  = (const float*)d_in[0];
    const float* wq = (const float*)d_in[1];
    const float* wk = (const float*)d_in[2];
    const float* wv = (const float*)d_in[3];
    const float* wo = (const float*)d_in[4];
    float* out = (float*)d_out;

    const int D = DMODEL;
    const int M = in_sizes[0] / D;  // B*S = 8192
    const int Bb = M / S_LEN;       // 2

    ushort* xb   = (ushort*)d_ws;
    ushort* W3b  = xb + (size_t)M * D;
    ushort* wob  = W3b + (size_t)NQKV * D;
    ushort* QKVb = wob + (size_t)D * D;
    ushort* Ob   = xb;  // overlay: xb dead after QKV GEMM

    const int nx8 = M * D / 8, nw8 = D * D / 8;
    const int ntot = nx8 + 4 * nw8;
    cvt_all<<<dim3((ntot + 255) / 256), dim3(256), 0, stream>>>(
        x, wq, wk, wv, wo, xb, W3b, wob, nx8, nw8);

    // Fused QKV projection: [M,3072] = xb @ W3b^T (proven 128x256 BK=64)
    gemm128<false><<<dim3(NQKV / 256, M / 128), dim3(256), 0, stream>>>(
        xb, W3b, QKVb, M, NQKV, D);

    swattn_mfma<<<dim3(S_LEN / WIN, NH, Bb), dim3(256), 0, stream>>>(QKVb, Ob);

    // Output projection: out[M,1024] = Ob @ wob^T (fp32 out, same structure)
    gemm128<true><<<dim3(D / 256, M / 128), dim3(256), 0, stream>>>(
        Ob, wob, out, M, D, D);
}

// Round 6
// 221.066 us; speedup vs baseline: 1.0633x; 1.0228x over previous
//
#include <hip/hip_runtime.h>

// Problem constants (match reference)
#define S_LEN 4096
#define DMODEL 1024
#define NH 16
#define DH 64
#define WIN 256
#define NQKV 3072  // fused QKV output width

typedef __attribute__((ext_vector_type(8))) short short8;
typedef __attribute__((ext_vector_type(4))) short sh4;
typedef __attribute__((ext_vector_type(4))) float floatx4;

__device__ __forceinline__ ushort f2bf(float f) {
    union { float f; unsigned int i; } x;
    x.f = f;
    unsigned int r = x.i + 0x7FFFu + ((x.i >> 16) & 1u);  // RNE
    return (ushort)(r >> 16);
}

// ---------------------------------------------------------------------------
// Fused fp32 -> bf16 convert for x, wq, wk, wv, wo in ONE dispatch.
// ---------------------------------------------------------------------------
__global__ __launch_bounds__(256) void cvt_all(const float* __restrict__ x,
                                               const float* __restrict__ wq,
                                               const float* __restrict__ wk,
                                               const float* __restrict__ wv,
                                               const float* __restrict__ wo,
                                               ushort* __restrict__ xb,
                                               ushort* __restrict__ W3b,
                                               ushort* __restrict__ wob,
                                               int nx8, int nw8) {
    int i = blockIdx.x * 256 + threadIdx.x;
    const float* src;
    ushort* dst;
    if (i < nx8) {
        src = x + (size_t)i * 8;            dst = xb + (size_t)i * 8;
    } else {
        int j = i - nx8;
        int which = j / nw8, r = j - which * nw8;
        if (which >= 4) return;
        const float* w4[4] = {wq, wk, wv, wo};
        src = w4[which] + (size_t)r * 8;
        dst = (which == 3 ? wob : W3b + (size_t)which * nw8 * 8) + (size_t)r * 8;
    }
    floatx4 f0 = *(const floatx4*)src;
    floatx4 f1 = *(const floatx4*)(src + 4);
    short8 v;
#pragma unroll
    for (int e = 0; e < 4; ++e) v[e] = (short)f2bf(f0[e]);
#pragma unroll
    for (int e = 0; e < 4; ++e) v[4 + e] = (short)f2bf(f1[e]);
    *(short8*)dst = v;
}

// ---------------------------------------------------------------------------
#define GLOAD16(src, dst)                                                     \
    __builtin_amdgcn_global_load_lds(                                         \
        (const __attribute__((address_space(1))) void*)(src),                 \
        (__attribute__((address_space(3))) void*)(dst), 16, 0, 0)

// ---------------------------------------------------------------------------
// Proven 128x256 BK=64 single-buffer GEMM (best measured QKV config:
// 61.5us / 849 TF effective, zero bank conflicts, FETCH 41MB with XCD
// swizzle). Used for BOTH projections. 2-barrier loop: deep-pipeline ports
// measured SLOWER on this shape (70.8/71.6us, R2/R3) — FROZEN as control.
// ---------------------------------------------------------------------------
template <bool OUTF32>
__global__ __launch_bounds__(256, 2) void gemm128(const ushort* __restrict__ A,
                                                  const ushort* __restrict__ W,
                                                  void* __restrict__ Cout,
                                                  int M, int N, int K) {
    __shared__ __align__(16) ushort As[128 * 64];  // 16 KB
    __shared__ __align__(16) ushort Ws[256 * 64];  // 32 KB

    const int tid = threadIdx.x;
    const int w = tid >> 6, l = tid & 63;

    // XCD-aware block swizzle (bijective when gridDim.y % 8 == 0).
    int bx, by;
    {
        const int nbx = gridDim.x, nby = gridDim.y;
        if ((nby & 7) == 0) {
            const int lin = blockIdx.y * nbx + blockIdx.x;
            const int rpb = nby >> 3;
            const int xcd = lin & 7, idx = lin >> 3;
            bx = idx / rpb;
            by = xcd * rpb + (idx - bx * rpb);
        } else {
            bx = blockIdx.x;
            by = blockIdx.y;
        }
    }
    const int bm0 = by * 128, bn0 = bx * 256;
    const int wm = (w >> 1) * 64, wn = (w & 1) * 128;
    const int lm = l & 15, quad = l >> 4;

    floatx4 acc[4][8] = {};

    // Staging: chunk c (16 B): row = c>>3, pos = c&7, global seg = pos^(row&7)
    // (both-sides XOR swizzle; reads use the same involution -> 0 conflicts).
    int arow[4], acol[4];
#pragma unroll
    for (int p = 0; p < 4; ++p) {
        int c = p * 256 + tid;
        arow[p] = c >> 3;
        acol[p] = (((c & 7) ^ (arow[p] & 7))) * 8;
    }
    int wrow[8], wcol[8];
#pragma unroll
    for (int p = 0; p < 8; ++p) {
        int c = p * 256 + tid;
        wrow[p] = c >> 3;
        wcol[p] = (((c & 7) ^ (wrow[p] & 7))) * 8;
    }

    for (int k0 = 0; k0 < K; k0 += 64) {
#pragma unroll
        for (int p = 0; p < 4; ++p)
            GLOAD16(A + (size_t)(bm0 + arow[p]) * K + k0 + acol[p],
                    As + p * 2048 + tid * 8);
#pragma unroll
        for (int p = 0; p < 8; ++p)
            GLOAD16(W + (size_t)(bn0 + wrow[p]) * K + k0 + wcol[p],
                    Ws + p * 2048 + tid * 8);
        __syncthreads();  // drains vmcnt(0): staging complete

#pragma unroll
        for (int kk = 0; kk < 2; ++kk) {
            const int sseg = ((kk * 4 + quad) ^ (lm & 7)) * 8;
            short8 af[4], wf[8];
#pragma unroll
            for (int mi = 0; mi < 4; ++mi)
                af[mi] = *(const short8*)&As[(wm + mi * 16 + lm) * 64 + sseg];
#pragma unroll
            for (int ni = 0; ni < 8; ++ni)
                wf[ni] = *(const short8*)&Ws[(wn + ni * 16 + lm) * 64 + sseg];
#pragma unroll
            for (int mi = 0; mi < 4; ++mi)
#pragma unroll
                for (int ni = 0; ni < 8; ++ni)
                    acc[mi][ni] = __builtin_amdgcn_mfma_f32_16x16x32_bf16(
                        af[mi], wf[ni], acc[mi][ni], 0, 0, 0);
        }
        __syncthreads();  // frag reads done before next staging overwrites
    }

#pragma unroll
    for (int mi = 0; mi < 4; ++mi)
#pragma unroll
        for (int ni = 0; ni < 8; ++ni)
#pragma unroll
            for (int r = 0; r < 4; ++r) {
                int row = bm0 + wm + mi * 16 + quad * 4 + r;
                int col = bn0 + wn + ni * 16 + lm;
                if constexpr (OUTF32)
                    ((float*)Cout)[(size_t)row * N + col] = acc[mi][ni][r];
                else
                    ((ushort*)Cout)[(size_t)row * N + col] = f2bf(acc[mi][ni][r]);
            }
}

// ---------------------------------------------------------------------------
// MFMA sliding-window attention over fused QKV layout [M][3072].
// R6: Ps LDS round-trip ELIMINATED. Key insight: swapped QK^T puts the q
// index of st[kt][nq][r] at lane position lc — the SAME lane position the
// PV A-fragment needs its q index at. Only the key->k-slot order differs,
// and MFMA is invariant under a consistent k-slot permutation of BOTH
// operands. So V is staged with columns permuted within each 32-key group
// (p5 = ((k&12)>>2)*8 + ((k>>4)&1)*4 + (k&3), free index math), and the PV
// A-frag becomes an in-lane repack of st via v_cvt_pk_bf16_f32 (RNE,
// bit-identical to f2bf). Deletes: Ps (40KB LDS), per-group threadfence,
// 8 ds_write_b64 + 4 ds_read_b128 per group per wave, 96 VALU of manual
// cvt (now 16 cvt_pk). LDS 77.8KB -> 36.9KB: occupancy 2 -> 3-4 blocks/CU.
// K staged in LDS (K-direct measured worse, R4); T14 reg-prefetch kept (R5).
// ---------------------------------------------------------------------------
#define KSP 72    // Ks row stride (shorts)
#define VTP 136   // Vt row stride (shorts)

__global__ __launch_bounds__(256) void swattn_mfma(const ushort* __restrict__ QKV,
                                                   ushort* __restrict__ O) {
    __shared__ __align__(16) ushort Ks[128 * KSP];  // 18432 B  [key][d]
    __shared__ __align__(16) ushort Vt[64 * VTP];   // 17408 B  [pi(d)][perm(key)]
    __shared__ __align__(16) float lW[256];         // 1024 B

    const int j = blockIdx.x, h = blockIdx.y, b = blockIdx.z;
    const int tid = threadIdx.x;
    const int w = tid >> 6, l = tid & 63;
    const int quad = l >> 4, lc = l & 15;

    const size_t base = (size_t)b * S_LEN * NQKV + (size_t)h * DH;
    const ushort* Qp = QKV + base;               // row stride NQKV
    const ushort* Kp = QKV + base + DMODEL;
    const ushort* Vp = QKV + base + 2 * DMODEL;

    short8 qf[4][2];
#pragma unroll
    for (int nq = 0; nq < 4; ++nq)
#pragma unroll
        for (int kk = 0; kk < 2; ++kk)
            qf[nq][kk] = *(const short8*)(Qp +
                (size_t)(j * 256 + w * 64 + nq * 16 + lc) * NQKV + kk * 32 + quad * 8);

    floatx4 o[4][4] = {};
    float lsum[4] = {0.f, 0.f, 0.f, 0.f};

    const float sscale = 0.18033688011112042f;  // log2(e)/sqrt(64)
    const float M0 = 2.0f;                      // fixed shift (exact: shift-invariance)
    const int qlo = w * 64, qhi = w * 64 + 63;

    // Per-thread staging coordinates (chunk i: key = (i*256+tid)>>3, seg low3)
    int skey[4], sseg[4], svcol[4];
#pragma unroll
    for (int i = 0; i < 4; ++i) {
        int cc = i * 256 + tid;
        skey[i] = cc >> 3;
        sseg[i] = cc & 7;
        // V column permutation within each 32-key group: k-slot
        // p5 = quad(k)*8 + kt(k)*4 + r(k); matches the in-lane PV repack.
        int k = skey[i];
        svcol[i] = (k & 96) + ((k >> 2) & 3) * 8 + ((k >> 4) & 1) * 4 + (k & 3);
    }

    short8 kreg[4], vreg[4];
    const int c0 = (j == 0) ? 2 : 0;  // first chunk with kg0 >= 0
    {
        const int kg0 = (j - 1) * 256 + c0 * 128;
#pragma unroll
        for (int i = 0; i < 4; ++i) {
            kreg[i] = *(const short8*)(Kp + (size_t)(kg0 + skey[i]) * NQKV + sseg[i] * 8);
            vreg[i] = *(const short8*)(Vp + (size_t)(kg0 + skey[i]) * NQKV + sseg[i] * 8);
        }
    }

    for (int c = c0; c < 4; ++c) {
        __syncthreads();  // prev chunk's Ks/Vt reads done before overwrite
#pragma unroll
        for (int i = 0; i < 4; ++i) {
            *(short8*)&Ks[skey[i] * KSP + sseg[i] * 8] = kreg[i];
#pragma unroll
            for (int e = 0; e < 8; ++e)
                Vt[(e * 8 + sseg[i]) * VTP + svcol[i]] = (ushort)vreg[i][e];  // pi rows, perm cols
        }
        __syncthreads();

        if (c < 3) {  // T14: issue next chunk's loads; they land under compute
            const int kg0n = (j - 1) * 256 + (c + 1) * 128;
#pragma unroll
            for (int i = 0; i < 4; ++i) {
                kreg[i] = *(const short8*)(Kp + (size_t)(kg0n + skey[i]) * NQKV + sseg[i] * 8);
                vreg[i] = *(const short8*)(Vp + (size_t)(kg0n + skey[i]) * NQKV + sseg[i] * 8);
            }
        }

        const int krel0 = c * 128 - 256;
#pragma unroll
        for (int g = 0; g < 4; ++g) {
            const int k0 = krel0 + g * 32;
            if (k0 > qhi || k0 + 31 < qlo - 255) continue;

            // S^T = K·Q^T : D[key][q], with fully-masked-subtile skip
            floatx4 st[2][4];
            const floatx4 zero = {};
#pragma unroll
            for (int kt = 0; kt < 2; ++kt) {
                short8 kf0 = *(const short8*)&Ks[(g * 32 + kt * 16 + lc) * KSP + quad * 8];
                short8 kf1 = *(const short8*)&Ks[(g * 32 + kt * 16 + lc) * KSP + 32 + quad * 8];
#pragma unroll
                for (int nq = 0; nq < 4; ++nq) {
                    int kmin = k0 + kt * 16, qmin = qlo + nq * 16;
                    if (kmin > qmin + 15 || kmin + 270 < qmin) {  // fully masked
                        st[kt][nq] = zero;
                        continue;
                    }
                    st[kt][nq] = __builtin_amdgcn_mfma_f32_16x16x32_bf16(kf0, qf[nq][0], zero, 0, 0, 0);
                    st[kt][nq] = __builtin_amdgcn_mfma_f32_16x16x32_bf16(kf1, qf[nq][1], st[kt][nq], 0, 0, 0);
                }
            }
            // Softmax transform IN PLACE (st becomes P in f32)
#pragma unroll
            for (int kt = 0; kt < 2; ++kt)
#pragma unroll
                for (int nq = 0; nq < 4; ++nq) {
                    int kmin = k0 + kt * 16, qmin = qlo + nq * 16;
                    if (kmin > qmin + 15 || kmin + 270 < qmin) {           // fully masked
                        st[kt][nq] = zero;
                    } else if (kmin + 15 <= qmin && kmin + 240 >= qmin) {  // interior: no mask
#pragma unroll
                        for (int r = 0; r < 4; ++r) {
                            float p = exp2f(st[kt][nq][r] * sscale - M0);
                            lsum[nq] += p;
                            st[kt][nq][r] = p;
                        }
                    } else {                                               // boundary
#pragma unroll
                        for (int r = 0; r < 4; ++r) {
                            int krel = kmin + quad * 4 + r;  // C row = key
                            int qrel = qmin + lc;            // C col = q
                            bool valid = (krel <= qrel) && (krel + 255 >= qrel);
                            float p = valid ? exp2f(st[kt][nq][r] * sscale - M0) : 0.f;
                            lsum[nq] += p;
                            st[kt][nq][r] = p;
                        }
                    }
                }

            // O += P·V : A built IN-LANE from st (k-slot e <-> key
            // (e>>2)*16 + quad*4 + (e&3), matching Vt's column permutation)
            short8 vf[4];
#pragma unroll
            for (int nd = 0; nd < 4; ++nd) {
                int prow = (lc & 7) * 8 + nd * 2 + (lc >> 3);  // pi(nd*16+lc)
                vf[nd] = *(const short8*)&Vt[prow * VTP + g * 32 + quad * 8];
            }
#pragma unroll
            for (int mq = 0; mq < 4; ++mq) {
                int qmin = qlo + mq * 16;
                if (k0 > qmin + 15 || k0 + 286 < qmin) continue;  // group fully masked
                union { unsigned int u[4]; short8 s; } pk;
                asm("v_cvt_pk_bf16_f32 %0, %1, %2"
                    : "=v"(pk.u[0]) : "v"(st[0][mq][0]), "v"(st[0][mq][1]));
                asm("v_cvt_pk_bf16_f32 %0, %1, %2"
                    : "=v"(pk.u[1]) : "v"(st[0][mq][2]), "v"(st[0][mq][3]));
                asm("v_cvt_pk_bf16_f32 %0, %1, %2"
                    : "=v"(pk.u[2]) : "v"(st[1][mq][0]), "v"(st[1][mq][1]));
                asm("v_cvt_pk_bf16_f32 %0, %1, %2"
                    : "=v"(pk.u[3]) : "v"(st[1][mq][2]), "v"(st[1][mq][3]));
#pragma unroll
                for (int nd = 0; nd < 4; ++nd)
                    o[mq][nd] = __builtin_amdgcn_mfma_f32_16x16x32_bf16(pk.s, vf[nd], o[mq][nd], 0, 0, 0);
            }
        }
    }

#pragma unroll
    for (int nq = 0; nq < 4; ++nq) {
        lsum[nq] += __shfl_xor(lsum[nq], 16);
        lsum[nq] += __shfl_xor(lsum[nq], 32);
    }
    if (l < 16) {
#pragma unroll
        for (int nq = 0; nq < 4; ++nq) lW[w * 64 + nq * 16 + l] = lsum[nq];
    }
    __threadfence_block();
#pragma unroll
    for (int mq = 0; mq < 4; ++mq) {
        floatx4 lv = *(const floatx4*)&lW[w * 64 + mq * 16 + quad * 4];
#pragma unroll
        for (int r = 0; r < 4; ++r) {
            float inv = 1.f / lv[r];
            int token = j * 256 + w * 64 + mq * 16 + quad * 4 + r;
#pragma unroll
            for (int nd = 0; nd < 4; ++nd)
                O[(size_t)b * S_LEN * DMODEL + (size_t)token * DMODEL + h * DH + nd * 16 + lc] =
                    f2bf(o[mq][nd][r] * inv);
        }
    }
}

// ---------------------------------------------------------------------------
extern "C" void kernel_launch(void* const* d_in, const int* in_sizes, int n_in,
                              void* d_out, int out_size, void* d_ws, size_t ws_size,
                              hipStream_t stream) {
    const float* x  = (const float*)d_in[0];
    const float* wq = (const float*)d_in[1];
    const float* wk = (const float*)d_in[2];
    const float* wv = (const float*)d_in[3];
    const float* wo = (const float*)d_in[4];
    float* out = (float*)d_out;

    const int D = DMODEL;
    const int M = in_sizes[0] / D;  // B*S = 8192
    const int Bb = M / S_LEN;       // 2

    ushort* xb   = (ushort*)d_ws;
    ushort* W3b  = xb + (size_t)M * D;
    ushort* wob  = W3b + (size_t)NQKV * D;
    ushort* QKVb = wob + (size_t)D * D;
    ushort* Ob   = xb;  // overlay: xb dead after QKV GEMM

    const int nx8 = M * D / 8, nw8 = D * D / 8;
    const int ntot = nx8 + 4 * nw8;
    cvt_all<<<dim3((ntot + 255) / 256), dim3(256), 0, stream>>>(
        x, wq, wk, wv, wo, xb, W3b, wob, nx8, nw8);

    // Fused QKV projection: [M,3072] = xb @ W3b^T (proven 128x256 BK=64)
    gemm128<false><<<dim3(NQKV / 256, M / 128), dim3(256), 0, stream>>>(
        xb, W3b, QKVb, M, NQKV, D);

    swattn_mfma<<<dim3(S_LEN / WIN, NH, Bb), dim3(256), 0, stream>>>(QKVb, Ob);

    // Output projection: out[M,1024] = Ob @ wob^T (fp32 out, same structure)
    gemm128<true><<<dim3(D / 256, M / 128), dim3(256), 0, stream>>>(
        Ob, wob, out, M, D, D);
}

// Round 7
// 215.735 us; speedup vs baseline: 1.0895x; 1.0247x over previous
//
#include <hip/hip_runtime.h>

// Problem constants (match reference)
#define S_LEN 4096
#define DMODEL 1024
#define NH 16
#define DH 64
#define WIN 256
#define NQKV 3072  // fused QKV output width

typedef __attribute__((ext_vector_type(8))) short short8;
typedef __attribute__((ext_vector_type(4))) short sh4;
typedef __attribute__((ext_vector_type(4))) float floatx4;

__device__ __forceinline__ ushort f2bf(float f) {
    union { float f; unsigned int i; } x;
    x.f = f;
    unsigned int r = x.i + 0x7FFFu + ((x.i >> 16) & 1u);  // RNE
    return (ushort)(r >> 16);
}

// ---------------------------------------------------------------------------
// Fused fp32 -> bf16 convert for x, wq, wk, wv, wo in ONE dispatch.
// ---------------------------------------------------------------------------
__global__ __launch_bounds__(256) void cvt_all(const float* __restrict__ x,
                                               const float* __restrict__ wq,
                                               const float* __restrict__ wk,
                                               const float* __restrict__ wv,
                                               const float* __restrict__ wo,
                                               ushort* __restrict__ xb,
                                               ushort* __restrict__ W3b,
                                               ushort* __restrict__ wob,
                                               int nx8, int nw8) {
    int i = blockIdx.x * 256 + threadIdx.x;
    const float* src;
    ushort* dst;
    if (i < nx8) {
        src = x + (size_t)i * 8;            dst = xb + (size_t)i * 8;
    } else {
        int j = i - nx8;
        int which = j / nw8, r = j - which * nw8;
        if (which >= 4) return;
        const float* w4[4] = {wq, wk, wv, wo};
        src = w4[which] + (size_t)r * 8;
        dst = (which == 3 ? wob : W3b + (size_t)which * nw8 * 8) + (size_t)r * 8;
    }
    floatx4 f0 = *(const floatx4*)src;
    floatx4 f1 = *(const floatx4*)(src + 4);
    short8 v;
#pragma unroll
    for (int e = 0; e < 4; ++e) v[e] = (short)f2bf(f0[e]);
#pragma unroll
    for (int e = 0; e < 4; ++e) v[4 + e] = (short)f2bf(f1[e]);
    *(short8*)dst = v;
}

// ---------------------------------------------------------------------------
#define GLOAD16(src, dst)                                                     \
    __builtin_amdgcn_global_load_lds(                                         \
        (const __attribute__((address_space(1))) void*)(src),                 \
        (__attribute__((address_space(3))) void*)(dst), 16, 0, 0)

// ---------------------------------------------------------------------------
// 128x128 BK=64 single-buffer GEMM (R7). Tile-space data at this exact
// 2-barrier structure (learn_hip m103): 128²=912 > 128x256=823 TF — the
// smaller tile halves LDS (48->32KB) and acc VGPR, so 3-4 blocks/CU
// co-reside (vs ~2) and cross-block wave overlap hides the barrier drain.
// Preserved verified elements: BK=64, 0-conflict 8-slot XOR swizzle
// (identical row math), global_load_lds width-16 staging, bijective
// XCD-aware swizzle (nby=64 % 8 == 0). Deep-pipeline schedules measured
// SLOWER on this problem (R1/R2/R3) — structure stays 2-barrier.
// ---------------------------------------------------------------------------
template <bool OUTF32>
__global__ __launch_bounds__(256, 2) void gemm_t128(const ushort* __restrict__ A,
                                                    const ushort* __restrict__ W,
                                                    void* __restrict__ Cout,
                                                    int M, int N, int K) {
    __shared__ __align__(16) ushort As[128 * 64];  // 16 KB
    __shared__ __align__(16) ushort Ws[128 * 64];  // 16 KB

    const int tid = threadIdx.x;
    const int w = tid >> 6, l = tid & 63;

    // XCD-aware block swizzle (bijective when gridDim.y % 8 == 0).
    int bx, by;
    {
        const int nbx = gridDim.x, nby = gridDim.y;
        if ((nby & 7) == 0) {
            const int lin = blockIdx.y * nbx + blockIdx.x;
            const int rpb = nby >> 3;
            const int xcd = lin & 7, idx = lin >> 3;
            bx = idx / rpb;
            by = xcd * rpb + (idx - bx * rpb);
        } else {
            bx = blockIdx.x;
            by = blockIdx.y;
        }
    }
    const int bm0 = by * 128, bn0 = bx * 128;
    const int wm = (w >> 1) * 64, wn = (w & 1) * 64;
    const int lm = l & 15, quad = l >> 4;

    floatx4 acc[4][4] = {};

    // Staging: chunk c (16 B): row = c>>3, pos = c&7, global seg = pos^(row&7)
    // (both-sides XOR swizzle; reads use the same involution -> 0 conflicts).
    int srow[4], scol[4];
#pragma unroll
    for (int p = 0; p < 4; ++p) {
        int c = p * 256 + tid;
        srow[p] = c >> 3;
        scol[p] = (((c & 7) ^ (srow[p] & 7))) * 8;
    }

    for (int k0 = 0; k0 < K; k0 += 64) {
#pragma unroll
        for (int p = 0; p < 4; ++p)
            GLOAD16(A + (size_t)(bm0 + srow[p]) * K + k0 + scol[p],
                    As + p * 2048 + tid * 8);
#pragma unroll
        for (int p = 0; p < 4; ++p)
            GLOAD16(W + (size_t)(bn0 + srow[p]) * K + k0 + scol[p],
                    Ws + p * 2048 + tid * 8);
        __syncthreads();  // drains vmcnt(0): staging complete

#pragma unroll
        for (int kk = 0; kk < 2; ++kk) {
            const int sseg = ((kk * 4 + quad) ^ (lm & 7)) * 8;
            short8 af[4], wf[4];
#pragma unroll
            for (int mi = 0; mi < 4; ++mi)
                af[mi] = *(const short8*)&As[(wm + mi * 16 + lm) * 64 + sseg];
#pragma unroll
            for (int ni = 0; ni < 4; ++ni)
                wf[ni] = *(const short8*)&Ws[(wn + ni * 16 + lm) * 64 + sseg];
#pragma unroll
            for (int mi = 0; mi < 4; ++mi)
#pragma unroll
                for (int ni = 0; ni < 4; ++ni)
                    acc[mi][ni] = __builtin_amdgcn_mfma_f32_16x16x32_bf16(
                        af[mi], wf[ni], acc[mi][ni], 0, 0, 0);
        }
        __syncthreads();  // frag reads done before next staging overwrites
    }

#pragma unroll
    for (int mi = 0; mi < 4; ++mi)
#pragma unroll
        for (int ni = 0; ni < 4; ++ni)
#pragma unroll
            for (int r = 0; r < 4; ++r) {
                int row = bm0 + wm + mi * 16 + quad * 4 + r;
                int col = bn0 + wn + ni * 16 + lm;
                if constexpr (OUTF32)
                    ((float*)Cout)[(size_t)row * N + col] = acc[mi][ni][r];
                else
                    ((ushort*)Cout)[(size_t)row * N + col] = f2bf(acc[mi][ni][r]);
            }
}

// ---------------------------------------------------------------------------
// MFMA sliding-window attention over fused QKV layout [M][3072]. (R6 design,
// unchanged: Ps-free in-lane P repack via cvt_pk + V column permutation;
// K LDS-staged; T14 reg-prefetch of next chunk under compute.)
// ---------------------------------------------------------------------------
#define KSP 72    // Ks row stride (shorts)
#define VTP 136   // Vt row stride (shorts)

__global__ __launch_bounds__(256) void swattn_mfma(const ushort* __restrict__ QKV,
                                                   ushort* __restrict__ O) {
    __shared__ __align__(16) ushort Ks[128 * KSP];  // 18432 B  [key][d]
    __shared__ __align__(16) ushort Vt[64 * VTP];   // 17408 B  [pi(d)][perm(key)]
    __shared__ __align__(16) float lW[256];         // 1024 B

    const int j = blockIdx.x, h = blockIdx.y, b = blockIdx.z;
    const int tid = threadIdx.x;
    const int w = tid >> 6, l = tid & 63;
    const int quad = l >> 4, lc = l & 15;

    const size_t base = (size_t)b * S_LEN * NQKV + (size_t)h * DH;
    const ushort* Qp = QKV + base;               // row stride NQKV
    const ushort* Kp = QKV + base + DMODEL;
    const ushort* Vp = QKV + base + 2 * DMODEL;

    short8 qf[4][2];
#pragma unroll
    for (int nq = 0; nq < 4; ++nq)
#pragma unroll
        for (int kk = 0; kk < 2; ++kk)
            qf[nq][kk] = *(const short8*)(Qp +
                (size_t)(j * 256 + w * 64 + nq * 16 + lc) * NQKV + kk * 32 + quad * 8);

    floatx4 o[4][4] = {};
    float lsum[4] = {0.f, 0.f, 0.f, 0.f};

    const float sscale = 0.18033688011112042f;  // log2(e)/sqrt(64)
    const float M0 = 2.0f;                      // fixed shift (exact: shift-invariance)
    const int qlo = w * 64, qhi = w * 64 + 63;

    // Per-thread staging coordinates (chunk i: key = (i*256+tid)>>3, seg low3)
    int skey[4], sseg[4], svcol[4];
#pragma unroll
    for (int i = 0; i < 4; ++i) {
        int cc = i * 256 + tid;
        skey[i] = cc >> 3;
        sseg[i] = cc & 7;
        // V column permutation within each 32-key group: k-slot
        // p5 = quad(k)*8 + kt(k)*4 + r(k); matches the in-lane PV repack.
        int k = skey[i];
        svcol[i] = (k & 96) + ((k >> 2) & 3) * 8 + ((k >> 4) & 1) * 4 + (k & 3);
    }

    short8 kreg[4], vreg[4];
    const int c0 = (j == 0) ? 2 : 0;  // first chunk with kg0 >= 0
    {
        const int kg0 = (j - 1) * 256 + c0 * 128;
#pragma unroll
        for (int i = 0; i < 4; ++i) {
            kreg[i] = *(const short8*)(Kp + (size_t)(kg0 + skey[i]) * NQKV + sseg[i] * 8);
            vreg[i] = *(const short8*)(Vp + (size_t)(kg0 + skey[i]) * NQKV + sseg[i] * 8);
        }
    }

    for (int c = c0; c < 4; ++c) {
        __syncthreads();  // prev chunk's Ks/Vt reads done before overwrite
#pragma unroll
        for (int i = 0; i < 4; ++i) {
            *(short8*)&Ks[skey[i] * KSP + sseg[i] * 8] = kreg[i];
#pragma unroll
            for (int e = 0; e < 8; ++e)
                Vt[(e * 8 + sseg[i]) * VTP + svcol[i]] = (ushort)vreg[i][e];  // pi rows, perm cols
        }
        __syncthreads();

        if (c < 3) {  // T14: issue next chunk's loads; they land under compute
            const int kg0n = (j - 1) * 256 + (c + 1) * 128;
#pragma unroll
            for (int i = 0; i < 4; ++i) {
                kreg[i] = *(const short8*)(Kp + (size_t)(kg0n + skey[i]) * NQKV + sseg[i] * 8);
                vreg[i] = *(const short8*)(Vp + (size_t)(kg0n + skey[i]) * NQKV + sseg[i] * 8);
            }
        }

        const int krel0 = c * 128 - 256;
#pragma unroll
        for (int g = 0; g < 4; ++g) {
            const int k0 = krel0 + g * 32;
            if (k0 > qhi || k0 + 31 < qlo - 255) continue;

            // S^T = K·Q^T : D[key][q], with fully-masked-subtile skip
            floatx4 st[2][4];
            const floatx4 zero = {};
#pragma unroll
            for (int kt = 0; kt < 2; ++kt) {
                short8 kf0 = *(const short8*)&Ks[(g * 32 + kt * 16 + lc) * KSP + quad * 8];
                short8 kf1 = *(const short8*)&Ks[(g * 32 + kt * 16 + lc) * KSP + 32 + quad * 8];
#pragma unroll
                for (int nq = 0; nq < 4; ++nq) {
                    int kmin = k0 + kt * 16, qmin = qlo + nq * 16;
                    if (kmin > qmin + 15 || kmin + 270 < qmin) {  // fully masked
                        st[kt][nq] = zero;
                        continue;
                    }
                    st[kt][nq] = __builtin_amdgcn_mfma_f32_16x16x32_bf16(kf0, qf[nq][0], zero, 0, 0, 0);
                    st[kt][nq] = __builtin_amdgcn_mfma_f32_16x16x32_bf16(kf1, qf[nq][1], st[kt][nq], 0, 0, 0);
                }
            }
            // Softmax transform IN PLACE (st becomes P in f32)
#pragma unroll
            for (int kt = 0; kt < 2; ++kt)
#pragma unroll
                for (int nq = 0; nq < 4; ++nq) {
                    int kmin = k0 + kt * 16, qmin = qlo + nq * 16;
                    if (kmin > qmin + 15 || kmin + 270 < qmin) {           // fully masked
                        st[kt][nq] = zero;
                    } else if (kmin + 15 <= qmin && kmin + 240 >= qmin) {  // interior: no mask
#pragma unroll
                        for (int r = 0; r < 4; ++r) {
                            float p = exp2f(st[kt][nq][r] * sscale - M0);
                            lsum[nq] += p;
                            st[kt][nq][r] = p;
                        }
                    } else {                                               // boundary
#pragma unroll
                        for (int r = 0; r < 4; ++r) {
                            int krel = kmin + quad * 4 + r;  // C row = key
                            int qrel = qmin + lc;            // C col = q
                            bool valid = (krel <= qrel) && (krel + 255 >= qrel);
                            float p = valid ? exp2f(st[kt][nq][r] * sscale - M0) : 0.f;
                            lsum[nq] += p;
                            st[kt][nq][r] = p;
                        }
                    }
                }

            // O += P·V : A built IN-LANE from st (k-slot e <-> key
            // (e>>2)*16 + quad*4 + (e&3), matching Vt's column permutation)
            short8 vf[4];
#pragma unroll
            for (int nd = 0; nd < 4; ++nd) {
                int prow = (lc & 7) * 8 + nd * 2 + (lc >> 3);  // pi(nd*16+lc)
                vf[nd] = *(const short8*)&Vt[prow * VTP + g * 32 + quad * 8];
            }
#pragma unroll
            for (int mq = 0; mq < 4; ++mq) {
                int qmin = qlo + mq * 16;
                if (k0 > qmin + 15 || k0 + 286 < qmin) continue;  // group fully masked
                union { unsigned int u[4]; short8 s; } pk;
                asm("v_cvt_pk_bf16_f32 %0, %1, %2"
                    : "=v"(pk.u[0]) : "v"(st[0][mq][0]), "v"(st[0][mq][1]));
                asm("v_cvt_pk_bf16_f32 %0, %1, %2"
                    : "=v"(pk.u[1]) : "v"(st[0][mq][2]), "v"(st[0][mq][3]));
                asm("v_cvt_pk_bf16_f32 %0, %1, %2"
                    : "=v"(pk.u[2]) : "v"(st[1][mq][0]), "v"(st[1][mq][1]));
                asm("v_cvt_pk_bf16_f32 %0, %1, %2"
                    : "=v"(pk.u[3]) : "v"(st[1][mq][2]), "v"(st[1][mq][3]));
#pragma unroll
                for (int nd = 0; nd < 4; ++nd)
                    o[mq][nd] = __builtin_amdgcn_mfma_f32_16x16x32_bf16(pk.s, vf[nd], o[mq][nd], 0, 0, 0);
            }
        }
    }

#pragma unroll
    for (int nq = 0; nq < 4; ++nq) {
        lsum[nq] += __shfl_xor(lsum[nq], 16);
        lsum[nq] += __shfl_xor(lsum[nq], 32);
    }
    if (l < 16) {
#pragma unroll
        for (int nq = 0; nq < 4; ++nq) lW[w * 64 + nq * 16 + l] = lsum[nq];
    }
    __threadfence_block();
#pragma unroll
    for (int mq = 0; mq < 4; ++mq) {
        floatx4 lv = *(const floatx4*)&lW[w * 64 + mq * 16 + quad * 4];
#pragma unroll
        for (int r = 0; r < 4; ++r) {
            float inv = 1.f / lv[r];
            int token = j * 256 + w * 64 + mq * 16 + quad * 4 + r;
#pragma unroll
            for (int nd = 0; nd < 4; ++nd)
                O[(size_t)b * S_LEN * DMODEL + (size_t)token * DMODEL + h * DH + nd * 16 + lc] =
                    f2bf(o[mq][nd][r] * inv);
        }
    }
}

// ---------------------------------------------------------------------------
extern "C" void kernel_launch(void* const* d_in, const int* in_sizes, int n_in,
                              void* d_out, int out_size, void* d_ws, size_t ws_size,
                              hipStream_t stream) {
    const float* x  = (const float*)d_in[0];
    const float* wq = (const float*)d_in[1];
    const float* wk = (const float*)d_in[2];
    const float* wv = (const float*)d_in[3];
    const float* wo = (const float*)d_in[4];
    float* out = (float*)d_out;

    const int D = DMODEL;
    const int M = in_sizes[0] / D;  // B*S = 8192
    const int Bb = M / S_LEN;       // 2

    ushort* xb   = (ushort*)d_ws;
    ushort* W3b  = xb + (size_t)M * D;
    ushort* wob  = W3b + (size_t)NQKV * D;
    ushort* QKVb = wob + (size_t)D * D;
    ushort* Ob   = xb;  // overlay: xb dead after QKV GEMM

    const int nx8 = M * D / 8, nw8 = D * D / 8;
    const int ntot = nx8 + 4 * nw8;
    cvt_all<<<dim3((ntot + 255) / 256), dim3(256), 0, stream>>>(
        x, wq, wk, wv, wo, xb, W3b, wob, nx8, nw8);

    // Fused QKV projection: [M,3072] = xb @ W3b^T (128² tile, 6 exact rounds)
    gemm_t128<false><<<dim3(NQKV / 128, M / 128), dim3(256), 0, stream>>>(
        xb, W3b, QKVb, M, NQKV, D);

    swattn_mfma<<<dim3(S_LEN / WIN, NH, Bb), dim3(256), 0, stream>>>(QKVb, Ob);

    // Output projection: out[M,1024] = Ob @ wob^T (128² tile, 2 exact rounds)
    gemm_t128<true><<<dim3(D / 128, M / 128), dim3(256), 0, stream>>>(
        Ob, wob, out, M, D, D);
}

// Round 8
// 207.235 us; speedup vs baseline: 1.1342x; 1.0410x over previous
//
#include <hip/hip_runtime.h>

// Problem constants (match reference)
#define S_LEN 4096
#define DMODEL 1024
#define NH 16
#define DH 64
#define WIN 256
#define NQKV 3072  // fused QKV output width

typedef __attribute__((ext_vector_type(8))) short short8;
typedef __attribute__((ext_vector_type(4))) short sh4;
typedef __attribute__((ext_vector_type(4))) float floatx4;

__device__ __forceinline__ ushort f2bf(float f) {
    union { float f; unsigned int i; } x;
    x.f = f;
    unsigned int r = x.i + 0x7FFFu + ((x.i >> 16) & 1u);  // RNE
    return (ushort)(r >> 16);
}

// ---------------------------------------------------------------------------
// Fused fp32 -> bf16 convert for x, wq, wk, wv, wo in ONE dispatch.
// ---------------------------------------------------------------------------
__global__ __launch_bounds__(256) void cvt_all(const float* __restrict__ x,
                                               const float* __restrict__ wq,
                                               const float* __restrict__ wk,
                                               const float* __restrict__ wv,
                                               const float* __restrict__ wo,
                                               ushort* __restrict__ xb,
                                               ushort* __restrict__ W3b,
                                               ushort* __restrict__ wob,
                                               int nx8, int nw8) {
    int i = blockIdx.x * 256 + threadIdx.x;
    const float* src;
    ushort* dst;
    if (i < nx8) {
        src = x + (size_t)i * 8;            dst = xb + (size_t)i * 8;
    } else {
        int j = i - nx8;
        int which = j / nw8, r = j - which * nw8;
        if (which >= 4) return;
        const float* w4[4] = {wq, wk, wv, wo};
        src = w4[which] + (size_t)r * 8;
        dst = (which == 3 ? wob : W3b + (size_t)which * nw8 * 8) + (size_t)r * 8;
    }
    floatx4 f0 = *(const floatx4*)src;
    floatx4 f1 = *(const floatx4*)(src + 4);
    short8 v;
#pragma unroll
    for (int e = 0; e < 4; ++e) v[e] = (short)f2bf(f0[e]);
#pragma unroll
    for (int e = 0; e < 4; ++e) v[4 + e] = (short)f2bf(f1[e]);
    *(short8*)dst = v;
}

// ---------------------------------------------------------------------------
#define GLOAD16(src, dst)                                                     \
    __builtin_amdgcn_global_load_lds(                                         \
        (const __attribute__((address_space(1))) void*)(src),                 \
        (__attribute__((address_space(3))) void*)(dst), 16, 0, 0)

// ---------------------------------------------------------------------------
// 128x128 BK=64 single-buffer GEMM — FROZEN (R7 measured: QKV 53.2us/969TF,
// MfmaUtil 39.6%, 0 bank conflicts, FETCH 41MB). Verified elements: BK=64,
// 0-conflict 8-slot XOR swizzle, width-16 global_load_lds, bijective XCD
// swizzle. Deep-pipeline ports measured slower (R1/R2/R3); 128x256 measured
// slower (R4-R6). Do not touch.
// ---------------------------------------------------------------------------
template <bool OUTF32>
__global__ __launch_bounds__(256, 2) void gemm_t128(const ushort* __restrict__ A,
                                                    const ushort* __restrict__ W,
                                                    void* __restrict__ Cout,
                                                    int M, int N, int K) {
    __shared__ __align__(16) ushort As[128 * 64];  // 16 KB
    __shared__ __align__(16) ushort Ws[128 * 64];  // 16 KB

    const int tid = threadIdx.x;
    const int w = tid >> 6, l = tid & 63;

    // XCD-aware block swizzle (bijective when gridDim.y % 8 == 0).
    int bx, by;
    {
        const int nbx = gridDim.x, nby = gridDim.y;
        if ((nby & 7) == 0) {
            const int lin = blockIdx.y * nbx + blockIdx.x;
            const int rpb = nby >> 3;
            const int xcd = lin & 7, idx = lin >> 3;
            bx = idx / rpb;
            by = xcd * rpb + (idx - bx * rpb);
        } else {
            bx = blockIdx.x;
            by = blockIdx.y;
        }
    }
    const int bm0 = by * 128, bn0 = bx * 128;
    const int wm = (w >> 1) * 64, wn = (w & 1) * 64;
    const int lm = l & 15, quad = l >> 4;

    floatx4 acc[4][4] = {};

    // Staging: chunk c (16 B): row = c>>3, pos = c&7, global seg = pos^(row&7)
    int srow[4], scol[4];
#pragma unroll
    for (int p = 0; p < 4; ++p) {
        int c = p * 256 + tid;
        srow[p] = c >> 3;
        scol[p] = (((c & 7) ^ (srow[p] & 7))) * 8;
    }

    for (int k0 = 0; k0 < K; k0 += 64) {
#pragma unroll
        for (int p = 0; p < 4; ++p)
            GLOAD16(A + (size_t)(bm0 + srow[p]) * K + k0 + scol[p],
                    As + p * 2048 + tid * 8);
#pragma unroll
        for (int p = 0; p < 4; ++p)
            GLOAD16(W + (size_t)(bn0 + srow[p]) * K + k0 + scol[p],
                    Ws + p * 2048 + tid * 8);
        __syncthreads();  // drains vmcnt(0): staging complete

#pragma unroll
        for (int kk = 0; kk < 2; ++kk) {
            const int sseg = ((kk * 4 + quad) ^ (lm & 7)) * 8;
            short8 af[4], wf[4];
#pragma unroll
            for (int mi = 0; mi < 4; ++mi)
                af[mi] = *(const short8*)&As[(wm + mi * 16 + lm) * 64 + sseg];
#pragma unroll
            for (int ni = 0; ni < 4; ++ni)
                wf[ni] = *(const short8*)&Ws[(wn + ni * 16 + lm) * 64 + sseg];
#pragma unroll
            for (int mi = 0; mi < 4; ++mi)
#pragma unroll
                for (int ni = 0; ni < 4; ++ni)
                    acc[mi][ni] = __builtin_amdgcn_mfma_f32_16x16x32_bf16(
                        af[mi], wf[ni], acc[mi][ni], 0, 0, 0);
        }
        __syncthreads();  // frag reads done before next staging overwrites
    }

#pragma unroll
    for (int mi = 0; mi < 4; ++mi)
#pragma unroll
        for (int ni = 0; ni < 4; ++ni)
#pragma unroll
            for (int r = 0; r < 4; ++r) {
                int row = bm0 + wm + mi * 16 + quad * 4 + r;
                int col = bn0 + wn + ni * 16 + lm;
                if constexpr (OUTF32)
                    ((float*)Cout)[(size_t)row * N + col] = acc[mi][ni][r];
                else
                    ((ushort*)Cout)[(size_t)row * N + col] = f2bf(acc[mi][ni][r]);
            }
}

// ---------------------------------------------------------------------------
// MFMA sliding-window attention over fused QKV layout [M][3072].
// R8: query block halved 256->128 (grid 512->1024 blocks = 4 blocks/CU,
// ~16 waves/CU vs 8). Rationale: the per-wave QK->softmax->PV chain is
// serial and softmax-VALU dominates (~32 v_exp/group); MFMA and VALU are
// separate pipes, so more co-resident waves/SIMD hide each other's phases.
// Per-wave state halves (qf/o/st), so 3-4 waves/SIMD is VGPR-feasible.
// Window = 3 chunks of 128 keys [Q0-256, Q0+127]; identical mask formulas
// in Q0-relative coords; same Ks/Vt layouts, svcol permutation, in-lane
// cvt_pk P repack (R6), T14 reg-prefetch (R5).
// ---------------------------------------------------------------------------
#define KSP 72    // Ks row stride (shorts)
#define VTP 136   // Vt row stride (shorts)

__global__ __launch_bounds__(256) void swattn_mfma(const ushort* __restrict__ QKV,
                                                   ushort* __restrict__ O) {
    __shared__ __align__(16) ushort Ks[128 * KSP];  // 18432 B  [key][d]
    __shared__ __align__(16) ushort Vt[64 * VTP];   // 17408 B  [pi(d)][perm(key)]
    __shared__ __align__(16) float lW[128];         // 512 B

    const int jq = blockIdx.x, h = blockIdx.y, b = blockIdx.z;
    const int tid = threadIdx.x;
    const int w = tid >> 6, l = tid & 63;
    const int quad = l >> 4, lc = l & 15;

    const int Q0 = jq * 128;  // block's query base

    const size_t base = (size_t)b * S_LEN * NQKV + (size_t)h * DH;
    const ushort* Qp = QKV + base;               // row stride NQKV
    const ushort* Kp = QKV + base + DMODEL;
    const ushort* Vp = QKV + base + 2 * DMODEL;

    short8 qf[2][2];
#pragma unroll
    for (int nq = 0; nq < 2; ++nq)
#pragma unroll
        for (int kk = 0; kk < 2; ++kk)
            qf[nq][kk] = *(const short8*)(Qp +
                (size_t)(Q0 + w * 32 + nq * 16 + lc) * NQKV + kk * 32 + quad * 8);

    floatx4 o[2][4] = {};
    float lsum[2] = {0.f, 0.f};

    const float sscale = 0.18033688011112042f;  // log2(e)/sqrt(64)
    const float M0 = 2.0f;                      // fixed shift (exact: shift-invariance)
    const int qlo = w * 32, qhi = w * 32 + 31;  // Q0-relative

    // Per-thread staging coordinates (chunk i: key = (i*256+tid)>>3, seg low3)
    int skey[4], sseg[4], svcol[4];
#pragma unroll
    for (int i = 0; i < 4; ++i) {
        int cc = i * 256 + tid;
        skey[i] = cc >> 3;
        sseg[i] = cc & 7;
        // V column permutation within each 32-key group: k-slot
        // p5 = quad(k)*8 + kt(k)*4 + r(k); matches the in-lane PV repack.
        int k = skey[i];
        svcol[i] = (k & 96) + ((k >> 2) & 3) * 8 + ((k >> 4) & 1) * 4 + (k & 3);
    }

    // Chunks c in [c0, 2]: keys kg0 = Q0 - 256 + c*128 (>= 0 iff c >= c0)
    const int c0 = (Q0 >= 256) ? 0 : ((Q0 >= 128) ? 1 : 2);

    short8 kreg[4], vreg[4];
    {
        const int kg0 = Q0 - 256 + c0 * 128;
#pragma unroll
        for (int i = 0; i < 4; ++i) {
            kreg[i] = *(const short8*)(Kp + (size_t)(kg0 + skey[i]) * NQKV + sseg[i] * 8);
            vreg[i] = *(const short8*)(Vp + (size_t)(kg0 + skey[i]) * NQKV + sseg[i] * 8);
        }
    }

    for (int c = c0; c < 3; ++c) {
        __syncthreads();  // prev chunk's Ks/Vt reads done before overwrite
#pragma unroll
        for (int i = 0; i < 4; ++i) {
            *(short8*)&Ks[skey[i] * KSP + sseg[i] * 8] = kreg[i];
#pragma unroll
            for (int e = 0; e < 8; ++e)
                Vt[(e * 8 + sseg[i]) * VTP + svcol[i]] = (ushort)vreg[i][e];  // pi rows, perm cols
        }
        __syncthreads();

        if (c < 2) {  // T14: issue next chunk's loads; they land under compute
            const int kg0n = Q0 - 256 + (c + 1) * 128;
#pragma unroll
            for (int i = 0; i < 4; ++i) {
                kreg[i] = *(const short8*)(Kp + (size_t)(kg0n + skey[i]) * NQKV + sseg[i] * 8);
                vreg[i] = *(const short8*)(Vp + (size_t)(kg0n + skey[i]) * NQKV + sseg[i] * 8);
            }
        }

        const int krel0 = c * 128 - 256;
#pragma unroll
        for (int g = 0; g < 4; ++g) {
            const int k0 = krel0 + g * 32;
            if (k0 > qhi || k0 + 31 < qlo - 255) continue;

            // S^T = K·Q^T : D[key][q], with fully-masked-subtile skip
            floatx4 st[2][2];
            const floatx4 zero = {};
#pragma unroll
            for (int kt = 0; kt < 2; ++kt) {
                short8 kf0 = *(const short8*)&Ks[(g * 32 + kt * 16 + lc) * KSP + quad * 8];
                short8 kf1 = *(const short8*)&Ks[(g * 32 + kt * 16 + lc) * KSP + 32 + quad * 8];
#pragma unroll
                for (int nq = 0; nq < 2; ++nq) {
                    int kmin = k0 + kt * 16, qmin = qlo + nq * 16;
                    if (kmin > qmin + 15 || kmin + 270 < qmin) {  // fully masked
                        st[kt][nq] = zero;
                        continue;
                    }
                    st[kt][nq] = __builtin_amdgcn_mfma_f32_16x16x32_bf16(kf0, qf[nq][0], zero, 0, 0, 0);
                    st[kt][nq] = __builtin_amdgcn_mfma_f32_16x16x32_bf16(kf1, qf[nq][1], st[kt][nq], 0, 0, 0);
                }
            }
            // Softmax transform IN PLACE (st becomes P in f32)
#pragma unroll
            for (int kt = 0; kt < 2; ++kt)
#pragma unroll
                for (int nq = 0; nq < 2; ++nq) {
                    int kmin = k0 + kt * 16, qmin = qlo + nq * 16;
                    if (kmin > qmin + 15 || kmin + 270 < qmin) {           // fully masked
                        st[kt][nq] = zero;
                    } else if (kmin + 15 <= qmin && kmin + 240 >= qmin) {  // interior: no mask
#pragma unroll
                        for (int r = 0; r < 4; ++r) {
                            float p = exp2f(st[kt][nq][r] * sscale - M0);
                            lsum[nq] += p;
                            st[kt][nq][r] = p;
                        }
                    } else {                                               // boundary
#pragma unroll
                        for (int r = 0; r < 4; ++r) {
                            int krel = kmin + quad * 4 + r;  // C row = key
                            int qrel = qmin + lc;            // C col = q
                            bool valid = (krel <= qrel) && (krel + 255 >= qrel);
                            float p = valid ? exp2f(st[kt][nq][r] * sscale - M0) : 0.f;
                            lsum[nq] += p;
                            st[kt][nq][r] = p;
                        }
                    }
                }

            // O += P·V : A built IN-LANE from st (k-slot e <-> key
            // (e>>2)*16 + quad*4 + (e&3), matching Vt's column permutation)
            short8 vf[4];
#pragma unroll
            for (int nd = 0; nd < 4; ++nd) {
                int prow = (lc & 7) * 8 + nd * 2 + (lc >> 3);  // pi(nd*16+lc)
                vf[nd] = *(const short8*)&Vt[prow * VTP + g * 32 + quad * 8];
            }
#pragma unroll
            for (int mq = 0; mq < 2; ++mq) {
                int qmin = qlo + mq * 16;
                if (k0 > qmin + 15 || k0 + 286 < qmin) continue;  // group fully masked
                union { unsigned int u[4]; short8 s; } pk;
                asm("v_cvt_pk_bf16_f32 %0, %1, %2"
                    : "=v"(pk.u[0]) : "v"(st[0][mq][0]), "v"(st[0][mq][1]));
                asm("v_cvt_pk_bf16_f32 %0, %1, %2"
                    : "=v"(pk.u[1]) : "v"(st[0][mq][2]), "v"(st[0][mq][3]));
                asm("v_cvt_pk_bf16_f32 %0, %1, %2"
                    : "=v"(pk.u[2]) : "v"(st[1][mq][0]), "v"(st[1][mq][1]));
                asm("v_cvt_pk_bf16_f32 %0, %1, %2"
                    : "=v"(pk.u[3]) : "v"(st[1][mq][2]), "v"(st[1][mq][3]));
#pragma unroll
                for (int nd = 0; nd < 4; ++nd)
                    o[mq][nd] = __builtin_amdgcn_mfma_f32_16x16x32_bf16(pk.s, vf[nd], o[mq][nd], 0, 0, 0);
            }
        }
    }

#pragma unroll
    for (int nq = 0; nq < 2; ++nq) {
        lsum[nq] += __shfl_xor(lsum[nq], 16);
        lsum[nq] += __shfl_xor(lsum[nq], 32);
    }
    if (l < 16) {
#pragma unroll
        for (int nq = 0; nq < 2; ++nq) lW[w * 32 + nq * 16 + l] = lsum[nq];
    }
    __threadfence_block();
#pragma unroll
    for (int mq = 0; mq < 2; ++mq) {
        floatx4 lv = *(const floatx4*)&lW[w * 32 + mq * 16 + quad * 4];
#pragma unroll
        for (int r = 0; r < 4; ++r) {
            float inv = 1.f / lv[r];
            int token = Q0 + w * 32 + mq * 16 + quad * 4 + r;
#pragma unroll
            for (int nd = 0; nd < 4; ++nd)
                O[(size_t)b * S_LEN * DMODEL + (size_t)token * DMODEL + h * DH + nd * 16 + lc] =
                    f2bf(o[mq][nd][r] * inv);
        }
    }
}

// ---------------------------------------------------------------------------
extern "C" void kernel_launch(void* const* d_in, const int* in_sizes, int n_in,
                              void* d_out, int out_size, void* d_ws, size_t ws_size,
                              hipStream_t stream) {
    const float* x  = (const float*)d_in[0];
    const float* wq = (const float*)d_in[1];
    const float* wk = (const float*)d_in[2];
    const float* wv = (const float*)d_in[3];
    const float* wo = (const float*)d_in[4];
    float* out = (float*)d_out;

    const int D = DMODEL;
    const int M = in_sizes[0] / D;  // B*S = 8192
    const int Bb = M / S_LEN;       // 2

    ushort* xb   = (ushort*)d_ws;
    ushort* W3b  = xb + (size_t)M * D;
    ushort* wob  = W3b + (size_t)NQKV * D;
    ushort* QKVb = wob + (size_t)D * D;
    ushort* Ob   = xb;  // overlay: xb dead after QKV GEMM

    const int nx8 = M * D / 8, nw8 = D * D / 8;
    const int ntot = nx8 + 4 * nw8;
    cvt_all<<<dim3((ntot + 255) / 256), dim3(256), 0, stream>>>(
        x, wq, wk, wv, wo, xb, W3b, wob, nx8, nw8);

    // Fused QKV projection: [M,3072] = xb @ W3b^T (frozen 128² structure)
    gemm_t128<false><<<dim3(NQKV / 128, M / 128), dim3(256), 0, stream>>>(
        xb, W3b, QKVb, M, NQKV, D);

    // Attention: 1024 blocks (128 queries each) = 4 blocks/CU
    swattn_mfma<<<dim3(S_LEN / 128, NH, Bb), dim3(256), 0, stream>>>(QKVb, Ob);

    // Output projection: out[M,1024] = Ob @ wob^T (fp32 out)
    gemm_t128<true><<<dim3(D / 128, M / 128), dim3(256), 0, stream>>>(
        Ob, wob, out, M, D, D);
}